// Round 9
// baseline (351.703 us; speedup 1.0000x reference)
//
#include <hip/hip_runtime.h>

// ---------------------------------------------------------------------------
// DualGCN v11: v9 structure + XCD-sliced SpMM gathers.
//   128-wide SpMMs split into (graph, 32-feature-slice) jobs, job = bx % 8
//   -> consecutive blocks round-robin across the 8 XCDs, so each XCD's
//   private 4 MB L2 serves ONE 3.2 MB slab slice (fits!) instead of the
//   full 12.8 MB x 2 graphs. Misses drop toward compulsory. No loop
//   doubling (v10's mistake): one depth-2 pipelined edge pass per thread,
//   4 lanes/row, 64 rows/block.
//   mixed launch: jobs 0-3 = graph-b slices, jobs 4-7 = Q row-quarters.
//   GEMMs / everything else: v9 verbatim (best: 292.6 us).
// 6 launches. N=50000, E=800000, H=128, OUT=64.
// ---------------------------------------------------------------------------

typedef short short8 __attribute__((ext_vector_type(8)));
typedef float floatx4 __attribute__((ext_vector_type(4)));

#define LDXP 136   // padded LDS row stride (bf16 units)

__device__ inline unsigned short f2bf(float f) {
  unsigned u = __builtin_bit_cast(unsigned, f);
  u += 0x7fffu + ((u >> 16) & 1u);      // round-to-nearest-even
  return (unsigned short)(u >> 16);
}
__device__ inline unsigned pack2(float a, float b) {
  return (unsigned)f2bf(a) | ((unsigned)f2bf(b) << 16);
}
__device__ inline float bf_lo(unsigned w) {
  return __builtin_bit_cast(float, w << 16);
}
__device__ inline float bf_hi(unsigned w) {
  return __builtin_bit_cast(float, w & 0xffff0000u);
}

// y=0: rowptr for graph a; y=1: rowptr for graph b; y=2: convert weights.
// Wo de-interleaved into Wo0 = Wo[:, :128] and Wo1 = Wo[:, 128:].
__global__ __launch_bounds__(256) void setup_kernel(
    const int* __restrict__ rowA, const int* __restrict__ rowB,
    int E, int n, int* __restrict__ rpa, int* __restrict__ rpb,
    const float* __restrict__ Wa0, const float* __restrict__ Wa1,
    const float* __restrict__ Wb0, const float* __restrict__ Wb1,
    const float* __restrict__ Wm,  const float* __restrict__ Wo,
    unsigned short* __restrict__ Wout)
{
  if (blockIdx.y == 2) {
    for (int i = blockIdx.x * 256 + threadIdx.x; i < 131072; i += gridDim.x * 256) {
      float v;
      if      (i < 16384)  v = Wa0[i];
      else if (i < 32768)  v = Wa1[i - 16384];
      else if (i < 49152)  v = Wb0[i - 32768];
      else if (i < 65536)  v = Wb1[i - 49152];
      else if (i < 114688) v = Wm[i - 65536];
      else {
        int o = i - 114688;           // [0, 16384)
        int half = o >> 13;           // 0 -> Wo0, 1 -> Wo1
        int idx = o & 8191;
        int r = idx >> 7, c = idx & 127;
        v = Wo[r * 256 + half * 128 + c];
      }
      Wout[i] = f2bf(v);
    }
    return;
  }
  int i = blockIdx.x * blockDim.x + threadIdx.x;
  if (i > n) return;
  const int* row = blockIdx.y ? rowB : rowA;
  int* rp = blockIdx.y ? rpb : rpa;
  int lo = 0, hi = E;
  while (lo < hi) {
    int mid = (lo + hi) >> 1;
    if (row[mid] < i) lo = mid + 1; else hi = mid;
  }
  rp[i] = lo;
}

// ---------------------------------------------------------------------------
// SpMM gather core (v5 depth-2 pipeline): a[0..7] += val[e]*X[col[e]*STRIDE
// + xoff .. +8]. col/val prefetched 2 batches ahead; 16 B per lane.
// ---------------------------------------------------------------------------
template <int STRIDE>
__device__ __forceinline__ void spmm_gather8(
    int e0, int e1, const int* __restrict__ col, const float* __restrict__ val,
    const unsigned short* __restrict__ X, int xoff, float a[8])
{
  auto gat = [&](int c) -> uint4 {
    return *(const uint4*)(X + (size_t)c * STRIDE + xoff);
  };
  auto fma1 = [&](float v, uint4 w) {
    a[0] = fmaf(v, bf_lo(w.x), a[0]); a[1] = fmaf(v, bf_hi(w.x), a[1]);
    a[2] = fmaf(v, bf_lo(w.y), a[2]); a[3] = fmaf(v, bf_hi(w.y), a[3]);
    a[4] = fmaf(v, bf_lo(w.z), a[4]); a[5] = fmaf(v, bf_hi(w.z), a[5]);
    a[6] = fmaf(v, bf_lo(w.w), a[6]); a[7] = fmaf(v, bf_hi(w.w), a[7]);
  };

  int e = e0;
  int epro = (e0 + 3) & ~3;             // align to 4 for vector col/val loads
  if (epro > e1) epro = e1;
  for (; e < epro; ++e) fma1(val[e], gat(col[e]));

  int nb = (e1 - e) >> 2;               // full 4-edge batches
  if (nb > 0) {
    int4   cA = *(const int4*)(col + e);
    float4 vA = *(const float4*)(val + e);
    int4   cB = cA; float4 vB = vA;
    if (nb > 1) { cB = *(const int4*)(col + e + 4); vB = *(const float4*)(val + e + 4); }
    uint4 w0 = gat(cA.x), w1 = gat(cA.y), w2 = gat(cA.z), w3 = gat(cA.w);
    for (int t = 0; t < nb - 1; ++t) {
      int4 cC = cB; float4 vC = vB;
      if (t + 2 < nb) {
        cC = *(const int4*)(col + e + 4 * (t + 2));
        vC = *(const float4*)(val + e + 4 * (t + 2));
      }
      uint4 u0 = gat(cB.x), u1 = gat(cB.y), u2 = gat(cB.z), u3 = gat(cB.w);
      fma1(vA.x, w0); fma1(vA.y, w1); fma1(vA.z, w2); fma1(vA.w, w3);
      vA = vB; vB = vC; cB = cC;
      w0 = u0; w1 = u1; w2 = u2; w3 = u3;
    }
    fma1(vA.x, w0); fma1(vA.y, w1); fma1(vA.z, w2); fma1(vA.w, w3);
    e += nb * 4;
  }
  for (; e < e1; ++e) fma1(val[e], gat(col[e]));
}

// one (graph, slice) job leg: rows 64/block, 4 lanes/row, 16 B gather at
// feature offset slice*32 + lane*8 of the 128-wide slab. bf16 out.
__device__ __forceinline__ void spmm_slice128(
    const int* __restrict__ rowptr, const int* __restrict__ col,
    const float* __restrict__ val, const unsigned short* __restrict__ X,
    unsigned short* __restrict__ Y, int n, int blk, int slice)
{
  const int g = blk * 64 + ((int)threadIdx.x >> 2);
  const int lane = threadIdx.x & 3;
  if (g >= n) return;
  const int xoff = slice * 32 + lane * 8;
  float a[8] = {0.f, 0.f, 0.f, 0.f, 0.f, 0.f, 0.f, 0.f};
  spmm_gather8<128>(rowptr[g], rowptr[g + 1], col, val, X, xoff, a);
  uint4 o;
  o.x = pack2(a[0], a[1]); o.y = pack2(a[2], a[3]);
  o.z = pack2(a[4], a[5]); o.w = pack2(a[6], a[7]);
  *(uint4*)(Y + (size_t)g * 128 + xoff) = o;
}

// jobs: bx%8 -> XCD round-robin. job>>2 = graph (0=a,1=b), job&3 = slice.
__global__ __launch_bounds__(256) void spmm_dual_sliced_kernel(
    const int* __restrict__ rpa, const int* __restrict__ cola,
    const float* __restrict__ vala, const unsigned short* __restrict__ Xa,
    unsigned short* __restrict__ Ya,
    const int* __restrict__ rpb, const int* __restrict__ colb,
    const float* __restrict__ valb, const unsigned short* __restrict__ Xb,
    unsigned short* __restrict__ Yb, int n)
{
  const int job = blockIdx.x & 7;
  const int blk = blockIdx.x >> 3;
  const int slice = job & 3;
  if (job < 4)
    spmm_slice128(rpa, cola, vala, Xa, Ya, n, blk, slice);
  else
    spmm_slice128(rpb, colb, valb, Xb, Yb, n, blk, slice);
}

// jobs 0-3: graph-b slices D->Yb; jobs 4-7: Q row-quarters -> Pout (f32,
// 64-wide, 8 lanes/row, 32 rows/block; Q slab 6.4 MB near-fits one L2).
__global__ __launch_bounds__(256) void spmm_mixed_sliced_kernel(
    const int* __restrict__ rpb, const int* __restrict__ colb,
    const float* __restrict__ valb, const unsigned short* __restrict__ D,
    unsigned short* __restrict__ Yb,
    const int* __restrict__ rpa, const int* __restrict__ cola,
    const float* __restrict__ vala, const unsigned short* __restrict__ Q,
    float* __restrict__ Pout, int n)
{
  const int job = blockIdx.x & 7;
  const int blk = blockIdx.x >> 3;
  if (job < 4) {
    spmm_slice128(rpb, colb, valb, D, Yb, n, blk, job);
  } else {
    const int q = job - 4;
    const int qn = (n + 3) >> 2;               // rows per quarter
    if (blk * 32 >= qn) return;
    const int g = q * qn + blk * 32 + ((int)threadIdx.x >> 3);
    if (g >= n || g >= (q + 1) * qn) return;
    const int lane = threadIdx.x & 7;
    float a[8] = {0.f, 0.f, 0.f, 0.f, 0.f, 0.f, 0.f, 0.f};
    spmm_gather8<64>(rpa[g], rpa[g + 1], cola, vala, Q, lane * 8, a);
    float4 o0; o0.x = a[0]; o0.y = a[1]; o0.z = a[2]; o0.w = a[3];
    float4 o1; o1.x = a[4]; o1.y = a[5]; o1.z = a[6]; o1.w = a[7];
    *(float4*)(Pout + (size_t)g * 64 + lane * 8) = o0;
    *(float4*)(Pout + (size_t)g * 64 + lane * 8 + 4) = o1;
  }
}

// ---------------------------------------------------------------------------
// GEMM building blocks (v9 verbatim). Block: 256 thr = 4 waves 2x2;
// tile 128 rows x HOUT. X operand in LDS; W fragments from global.
// ---------------------------------------------------------------------------
__device__ inline void stage_bf16(const unsigned short* __restrict__ Xp,
                                  unsigned short* Xs, int row0, int n,
                                  int rloc, int c8)
{
#pragma unroll
  for (int p = 0; p < 8; ++p) {
    int r = p * 16 + rloc;
    int gr = row0 + r;
    uint4 v = make_uint4(0u, 0u, 0u, 0u);
    if (gr < n) v = *(const uint4*)(Xp + (size_t)gr * 128 + c8);
    *(uint4*)(Xs + r * LDXP + c8) = v;
  }
}

template <int NT>
__device__ inline void mfma_phase(const unsigned short* __restrict__ W, int wld,
                                  const unsigned short* Xs,
                                  int wm, int wn, int l15, int quad,
                                  floatx4 (&acc)[4][NT])
{
#pragma unroll
  for (int k0 = 0; k0 < 128; k0 += 32) {
    const int ko = k0 + quad * 8;
    short8 aW[NT], bX[4];
#pragma unroll
    for (int j = 0; j < NT; ++j)
      aW[j] = *(const short8*)(W + (size_t)(wn * (16 * NT) + j * 16 + l15) * wld + ko);
#pragma unroll
    for (int i = 0; i < 4; ++i)
      bX[i] = *(const short8*)(Xs + (wm * 64 + i * 16 + l15) * LDXP + ko);
#pragma unroll
    for (int i = 0; i < 4; ++i)
#pragma unroll
      for (int j = 0; j < NT; ++j)
        acc[i][j] = __builtin_amdgcn_mfma_f32_16x16x32_bf16(aW[j], bX[i], acc[i][j], 0, 0, 0);
  }
}

// A = relu(x@W1.T+b1), C = relu(x@W2.T+b2) from fp32 x, shared X staging.
__global__ __launch_bounds__(256, 2) void gemm_dual_f32_kernel(
    const float* __restrict__ X, const unsigned short* __restrict__ W1,
    const unsigned short* __restrict__ W2, const float* __restrict__ b1,
    const float* __restrict__ b2, unsigned short* __restrict__ Y1,
    unsigned short* __restrict__ Y2, int n)
{
  constexpr int NT = 4;  // HOUT = 128
  __shared__ unsigned short Xs[128 * LDXP];
  const int tid = threadIdx.x;
  const int lane = tid & 63;
  const int wave = tid >> 6;
  const int wm = wave >> 1;
  const int wn = wave & 1;
  const int l15 = lane & 15;
  const int quad = lane >> 4;
  const int row0 = blockIdx.x * 128;
  const int c8 = (tid & 15) * 8;
  const int rloc = tid >> 4;

#pragma unroll
  for (int p = 0; p < 8; ++p) {
    int r = p * 16 + rloc;
    int gr = row0 + r;
    uint4 o = make_uint4(0u, 0u, 0u, 0u);
    if (gr < n) {
      float4 f0 = *(const float4*)(X + (size_t)gr * 128 + c8);
      float4 f1 = *(const float4*)(X + (size_t)gr * 128 + c8 + 4);
      o.x = pack2(f0.x, f0.y); o.y = pack2(f0.z, f0.w);
      o.z = pack2(f1.x, f1.y); o.w = pack2(f1.z, f1.w);
    }
    *(uint4*)(Xs + r * LDXP + c8) = o;
  }
  __syncthreads();

  for (int s = 0; s < 2; ++s) {
    const unsigned short* W = s ? W2 : W1;
    const float* b = s ? b2 : b1;
    unsigned short* Y = s ? Y2 : Y1;
    floatx4 acc[4][NT];
#pragma unroll
    for (int i = 0; i < 4; ++i)
#pragma unroll
      for (int j = 0; j < NT; ++j) acc[i][j] = (floatx4){0.f, 0.f, 0.f, 0.f};
    mfma_phase<NT>(W, 128, Xs, wm, wn, l15, quad, acc);
#pragma unroll
    for (int i = 0; i < 4; ++i) {
      int r = row0 + wm * 64 + i * 16 + l15;
      if (r >= n) continue;
#pragma unroll
      for (int j = 0; j < NT; ++j) {
        int c0 = wn * 64 + j * 16 + quad * 4;
        float4 bb = *(const float4*)(b + c0);
        float v0 = fmaxf(acc[i][j][0] + bb.x, 0.f);
        float v1 = fmaxf(acc[i][j][1] + bb.y, 0.f);
        float v2 = fmaxf(acc[i][j][2] + bb.z, 0.f);
        float v3 = fmaxf(acc[i][j][3] + bb.w, 0.f);
        uint2 o; o.x = pack2(v0, v1); o.y = pack2(v2, v3);
        *(uint2*)(Y + (size_t)r * 128 + c0) = o;
      }
    }
  }
}

// y=0: Q = (relu(B·Wa1^T+ba1))·Wo0^T (chained through LDS)
// y=1: D = relu(B2·Wb1^T+bb1)
__global__ __launch_bounds__(256, 2) void chain_g1_kernel(
    const unsigned short* __restrict__ B, const unsigned short* __restrict__ Wa1,
    const float* __restrict__ ba1, const unsigned short* __restrict__ Wo0,
    unsigned short* __restrict__ Q,
    const unsigned short* __restrict__ B2, const unsigned short* __restrict__ Wb1,
    const float* __restrict__ bb1, unsigned short* __restrict__ D, int n)
{
  __shared__ unsigned short Xs[128 * LDXP];
  const int tid = threadIdx.x;
  const int lane = tid & 63;
  const int wave = tid >> 6;
  const int wm = wave >> 1;
  const int wn = wave & 1;
  const int l15 = lane & 15;
  const int quad = lane >> 4;
  const int row0 = blockIdx.x * 128;
  const int c8 = (tid & 15) * 8;
  const int rloc = tid >> 4;

  if (blockIdx.y == 0) {
    stage_bf16(B, Xs, row0, n, rloc, c8);
    __syncthreads();

    floatx4 acc1[4][4];
#pragma unroll
    for (int i = 0; i < 4; ++i)
#pragma unroll
      for (int j = 0; j < 4; ++j) acc1[i][j] = (floatx4){0.f, 0.f, 0.f, 0.f};
    mfma_phase<4>(Wa1, 128, Xs, wm, wn, l15, quad, acc1);
    __syncthreads();   // all stage-1 reads of Xs done before overwrite

    // A2 = relu(acc1 + ba1) -> Xs (bf16)
#pragma unroll
    for (int i = 0; i < 4; ++i) {
      int r2 = wm * 64 + i * 16 + l15;
#pragma unroll
      for (int j = 0; j < 4; ++j) {
        int c2 = wn * 64 + j * 16 + quad * 4;
        float4 bb = *(const float4*)(ba1 + c2);
        float v0 = fmaxf(acc1[i][j][0] + bb.x, 0.f);
        float v1 = fmaxf(acc1[i][j][1] + bb.y, 0.f);
        float v2 = fmaxf(acc1[i][j][2] + bb.z, 0.f);
        float v3 = fmaxf(acc1[i][j][3] + bb.w, 0.f);
        uint2 o; o.x = pack2(v0, v1); o.y = pack2(v2, v3);
        *(uint2*)(Xs + r2 * LDXP + c2) = o;
      }
    }
    __syncthreads();

    floatx4 acc2[4][2];
#pragma unroll
    for (int i = 0; i < 4; ++i)
#pragma unroll
      for (int j = 0; j < 2; ++j) acc2[i][j] = (floatx4){0.f, 0.f, 0.f, 0.f};
    mfma_phase<2>(Wo0, 128, Xs, wm, wn, l15, quad, acc2);

#pragma unroll
    for (int i = 0; i < 4; ++i) {
      int r = row0 + wm * 64 + i * 16 + l15;
      if (r >= n) continue;
#pragma unroll
      for (int j = 0; j < 2; ++j) {
        int c0 = wn * 32 + j * 16 + quad * 4;
        uint2 o;
        o.x = pack2(acc2[i][j][0], acc2[i][j][1]);
        o.y = pack2(acc2[i][j][2], acc2[i][j][3]);
        *(uint2*)(Q + (size_t)r * 64 + c0) = o;
      }
    }
  } else {
    stage_bf16(B2, Xs, row0, n, rloc, c8);
    __syncthreads();

    floatx4 acc[4][4];
#pragma unroll
    for (int i = 0; i < 4; ++i)
#pragma unroll
      for (int j = 0; j < 4; ++j) acc[i][j] = (floatx4){0.f, 0.f, 0.f, 0.f};
    mfma_phase<4>(Wb1, 128, Xs, wm, wn, l15, quad, acc);

#pragma unroll
    for (int i = 0; i < 4; ++i) {
      int r = row0 + wm * 64 + i * 16 + l15;
      if (r >= n) continue;
#pragma unroll
      for (int j = 0; j < 4; ++j) {
        int c0 = wn * 64 + j * 16 + quad * 4;
        float4 bb = *(const float4*)(bb1 + c0);
        float v0 = fmaxf(acc[i][j][0] + bb.x, 0.f);
        float v1 = fmaxf(acc[i][j][1] + bb.y, 0.f);
        float v2 = fmaxf(acc[i][j][2] + bb.z, 0.f);
        float v3 = fmaxf(acc[i][j][3] + bb.w, 0.f);
        uint2 o; o.x = pack2(v0, v1); o.y = pack2(v2, v3);
        *(uint2*)(D + (size_t)r * 128 + c0) = o;
      }
    }
  }
}

// out = relu(C·Wm0 + D·Wm1 + G2·Wm2 + bm)·Wo1^T + bo + Pout  (A3 in LDS only)
__global__ __launch_bounds__(256, 2) void wm_final_kernel(
    const unsigned short* __restrict__ C, const unsigned short* __restrict__ D,
    const unsigned short* __restrict__ G2,
    const unsigned short* __restrict__ Wm, const float* __restrict__ bm,
    const unsigned short* __restrict__ Wo1, const float* __restrict__ bo,
    const float* __restrict__ Pout, float* __restrict__ out, int n)
{
  __shared__ unsigned short Xs[128 * LDXP];
  const int tid = threadIdx.x;
  const int lane = tid & 63;
  const int wave = tid >> 6;
  const int wm_ = wave >> 1;
  const int wn = wave & 1;
  const int l15 = lane & 15;
  const int quad = lane >> 4;
  const int row0 = blockIdx.x * 128;
  const int c8 = (tid & 15) * 8;
  const int rloc = tid >> 4;

  floatx4 acc[4][4];
#pragma unroll
  for (int i = 0; i < 4; ++i)
#pragma unroll
    for (int j = 0; j < 4; ++j) acc[i][j] = (floatx4){0.f, 0.f, 0.f, 0.f};

  const unsigned short* Xp[3] = {C, D, G2};
#pragma unroll
  for (int s = 0; s < 3; ++s) {
    if (s) __syncthreads();
    stage_bf16(Xp[s], Xs, row0, n, rloc, c8);
    __syncthreads();
    mfma_phase<4>(Wm + s * 128, 384, Xs, wm_, wn, l15, quad, acc);
  }
  __syncthreads();   // all K=384 reads done before A3 overwrite

  // A3 = relu(acc + bm) -> Xs (bf16)
#pragma unroll
  for (int i = 0; i < 4; ++i) {
    int r2 = wm_ * 64 + i * 16 + l15;
#pragma unroll
    for (int j = 0; j < 4; ++j) {
      int c2 = wn * 64 + j * 16 + quad * 4;
      float4 bb = *(const float4*)(bm + c2);
      float v0 = fmaxf(acc[i][j][0] + bb.x, 0.f);
      float v1 = fmaxf(acc[i][j][1] + bb.y, 0.f);
      float v2 = fmaxf(acc[i][j][2] + bb.z, 0.f);
      float v3 = fmaxf(acc[i][j][3] + bb.w, 0.f);
      uint2 o; o.x = pack2(v0, v1); o.y = pack2(v2, v3);
      *(uint2*)(Xs + r2 * LDXP + c2) = o;
    }
  }
  __syncthreads();

  floatx4 acc2[4][2];
#pragma unroll
  for (int i = 0; i < 4; ++i)
#pragma unroll
    for (int j = 0; j < 2; ++j) acc2[i][j] = (floatx4){0.f, 0.f, 0.f, 0.f};
  mfma_phase<2>(Wo1, 128, Xs, wm_, wn, l15, quad, acc2);

#pragma unroll
  for (int i = 0; i < 4; ++i) {
    int r = row0 + wm_ * 64 + i * 16 + l15;
    if (r >= n) continue;
#pragma unroll
    for (int j = 0; j < 2; ++j) {
      int c0 = wn * 32 + j * 16 + quad * 4;
      float4 bb = *(const float4*)(bo + c0);
      float4 pv = *(const float4*)(Pout + (size_t)r * 64 + c0);
      float4 o;
      o.x = acc2[i][j][0] + bb.x + pv.x;
      o.y = acc2[i][j][1] + bb.y + pv.y;
      o.z = acc2[i][j][2] + bb.z + pv.z;
      o.w = acc2[i][j][3] + bb.w + pv.w;
      *(float4*)(out + (size_t)r * 64 + c0) = o;
    }
  }
}

extern "C" void kernel_launch(void* const* d_in, const int* in_sizes, int n_in,
                              void* d_out, int out_size, void* d_ws, size_t ws_size,
                              hipStream_t stream)
{
  const float* x     = (const float*)d_in[0];
  const int*   row_a = (const int*)d_in[1];
  const int*   col_a = (const int*)d_in[2];
  const float* val_a = (const float*)d_in[3];
  const int*   row_b = (const int*)d_in[4];
  const int*   col_b = (const int*)d_in[5];
  const float* val_b = (const float*)d_in[6];
  const float* Wa0 = (const float*)d_in[7];  const float* ba0 = (const float*)d_in[8];
  const float* Wa1 = (const float*)d_in[9];  const float* ba1 = (const float*)d_in[10];
  const float* Wb0 = (const float*)d_in[11]; const float* bb0 = (const float*)d_in[12];
  const float* Wb1 = (const float*)d_in[13]; const float* bb1 = (const float*)d_in[14];
  const float* Wm  = (const float*)d_in[15]; const float* bm  = (const float*)d_in[16];
  const float* Wo  = (const float*)d_in[17]; const float* bo  = (const float*)d_in[18];
  float* out = (float*)d_out;

  const int n = in_sizes[0] / 128;   // 50000
  const int E = in_sizes[1];         // 800000

  char* ws = (char*)d_ws;
  size_t off = 0;
  auto alloc = [&](size_t bytes) {
    void* p = ws + off;
    off = (off + bytes + 255) & ~(size_t)255;
    return p;
  };
  int* rpa = (int*)alloc((size_t)(n + 1) * sizeof(int));
  int* rpb = (int*)alloc((size_t)(n + 1) * sizeof(int));
  unsigned short* Wcat = (unsigned short*)alloc(131072 * sizeof(unsigned short));
  const size_t slab = (size_t)n * 128 * sizeof(unsigned short);
  unsigned short* A  = (unsigned short*)alloc(slab);   // relu(x Wa0 + ba0)
  unsigned short* C  = (unsigned short*)alloc(slab);   // g0
  unsigned short* B  = (unsigned short*)alloc(slab);   // graph-a sp1 out / g2
  unsigned short* B2 = (unsigned short*)alloc(slab);   // graph-b sp1 out
  unsigned short* D  = (unsigned short*)alloc(slab);   // g1
  unsigned short* Q  = (unsigned short*)alloc((size_t)n * 64 * sizeof(unsigned short));
  float* Pout = (float*)alloc((size_t)n * 64 * sizeof(float)); // x_a @ Wo0^T

  const unsigned short* Wa0b = Wcat;
  const unsigned short* Wa1b = Wcat + 16384;
  const unsigned short* Wb0b = Wcat + 32768;
  const unsigned short* Wb1b = Wcat + 49152;
  const unsigned short* Wmb  = Wcat + 65536;   // [128, 384]
  const unsigned short* Wo0b = Wcat + 114688;
  const unsigned short* Wo1b = Wcat + 122880;

  dim3 blk(256);
  dim3 g_setup((n + 1 + 255) / 256, 3);
  dim3 g_lin((n + 127) / 128);
  dim3 g_cg((n + 127) / 128, 2);
  dim3 g_spx(((n + 63) / 64) * 8);   // 8 jobs interleaved (bx%8 -> XCD)

  setup_kernel<<<g_setup, blk, 0, stream>>>(row_a, row_b, E, n, rpa, rpb,
                                            Wa0, Wa1, Wb0, Wb1, Wm, Wo, Wcat);

  // A = relu(x Wa0^T + ba0), C = relu(x Wb0^T + bb0)
  gemm_dual_f32_kernel<<<g_lin, blk, 0, stream>>>(x, Wa0b, Wb0b, ba0, bb0, A, C, n);

  // spmm_a(A->B) || spmm_b(C->B2), XCD-sliced by (graph, feature-slice)
  spmm_dual_sliced_kernel<<<g_spx, blk, 0, stream>>>(
      rpa, col_a, val_a, A, B,
      rpb, col_b, val_b, C, B2, n);

  // chain: Q = relu(B Wa1^T + ba1) Wo0^T  ||  g1: D = relu(B2 Wb1^T + bb1)
  chain_g1_kernel<<<g_cg, blk, 0, stream>>>(
      B, Wa1b, ba1, Wo0b, Q,
      B2, Wb1b, bb1, D, n);

  // g2 = spmm_b(D) -> B (sliced)  ||  Pout = spmm_a(Q) (row-quartered)
  spmm_mixed_sliced_kernel<<<g_spx, blk, 0, stream>>>(
      rpb, col_b, val_b, D, B,
      rpa, col_a, val_a, Q, Pout, n);

  // out = relu(g0 Wm0 + g1 Wm1 + g2 Wm2 + bm) Wo1^T + bo + Pout
  wm_final_kernel<<<g_lin, blk, 0, stream>>>(
      C, D, B, Wmb, bm, Wo1b, bo, Pout, out, n);
}

// Round 10
// 320.921 us; speedup vs baseline: 1.0959x; 1.0959x over previous
//
#include <hip/hip_runtime.h>

// ---------------------------------------------------------------------------
// DualGCN v12: v9 (best, 292.6us) + non-temporal hints on SpMM streams.
//   col/val loads and Y/Pout stores in the SpMM are single-use streams that
//   churn each XCD's 4MB L2 and evict the randomly-gathered X lines (the
//   r9 post-mortem mechanism). __builtin_nontemporal_* keeps them out of
//   L2 -> more residence for gather lines -> fewer fabric fetches.
//   Everything else v9 verbatim.
// 6 launches. N=50000, E=800000, H=128, OUT=64.
// ---------------------------------------------------------------------------

typedef short short8 __attribute__((ext_vector_type(8)));
typedef float floatx4 __attribute__((ext_vector_type(4)));
typedef int   intx4   __attribute__((ext_vector_type(4)));
typedef float fltx4   __attribute__((ext_vector_type(4)));
typedef unsigned uintx4 __attribute__((ext_vector_type(4)));

#define LDXP 136   // padded LDS row stride (bf16 units)

__device__ inline unsigned short f2bf(float f) {
  unsigned u = __builtin_bit_cast(unsigned, f);
  u += 0x7fffu + ((u >> 16) & 1u);      // round-to-nearest-even
  return (unsigned short)(u >> 16);
}
__device__ inline unsigned pack2(float a, float b) {
  return (unsigned)f2bf(a) | ((unsigned)f2bf(b) << 16);
}
__device__ inline float bf_lo(unsigned w) {
  return __builtin_bit_cast(float, w << 16);
}
__device__ inline float bf_hi(unsigned w) {
  return __builtin_bit_cast(float, w & 0xffff0000u);
}

// y=0: rowptr for graph a; y=1: rowptr for graph b; y=2: convert weights.
// Wo de-interleaved into Wo0 = Wo[:, :128] and Wo1 = Wo[:, 128:].
__global__ __launch_bounds__(256) void setup_kernel(
    const int* __restrict__ rowA, const int* __restrict__ rowB,
    int E, int n, int* __restrict__ rpa, int* __restrict__ rpb,
    const float* __restrict__ Wa0, const float* __restrict__ Wa1,
    const float* __restrict__ Wb0, const float* __restrict__ Wb1,
    const float* __restrict__ Wm,  const float* __restrict__ Wo,
    unsigned short* __restrict__ Wout)
{
  if (blockIdx.y == 2) {
    for (int i = blockIdx.x * 256 + threadIdx.x; i < 131072; i += gridDim.x * 256) {
      float v;
      if      (i < 16384)  v = Wa0[i];
      else if (i < 32768)  v = Wa1[i - 16384];
      else if (i < 49152)  v = Wb0[i - 32768];
      else if (i < 65536)  v = Wb1[i - 49152];
      else if (i < 114688) v = Wm[i - 65536];
      else {
        int o = i - 114688;           // [0, 16384)
        int half = o >> 13;           // 0 -> Wo0, 1 -> Wo1
        int idx = o & 8191;
        int r = idx >> 7, c = idx & 127;
        v = Wo[r * 256 + half * 128 + c];
      }
      Wout[i] = f2bf(v);
    }
    return;
  }
  int i = blockIdx.x * blockDim.x + threadIdx.x;
  if (i > n) return;
  const int* row = blockIdx.y ? rowB : rowA;
  int* rp = blockIdx.y ? rpb : rpa;
  int lo = 0, hi = E;
  while (lo < hi) {
    int mid = (lo + hi) >> 1;
    if (row[mid] < i) lo = mid + 1; else hi = mid;
  }
  rp[i] = lo;
}

// ---------------------------------------------------------------------------
// SpMM row body (v5 depth-2 pipeline + NT streams):
// Y[g,:] = sum_e val[e] * X[col[e],:]
// WIDTH bf16 features; WIDTH/8 lanes per row, 16 B gather per lane.
// col/val loaded non-temporally (single-use streams); X gathers cached.
// ---------------------------------------------------------------------------
template <int WIDTH, bool OUTF32>
__device__ __forceinline__ void spmm_rows(
    const int* __restrict__ rowptr, const int* __restrict__ col,
    const float* __restrict__ val, const unsigned short* __restrict__ X,
    void* __restrict__ Yv, int n, int bx)
{
  constexpr int LPR = WIDTH / 8;        // lanes per row
  constexpr int GPB = 256 / LPR;        // row-groups per block
  int g = bx * GPB + ((int)threadIdx.x / LPR);
  int lane = threadIdx.x & (LPR - 1);
  if (g >= n) return;
  int e0 = rowptr[g], e1 = rowptr[g + 1];

  float a0 = 0.f, a1 = 0.f, a2 = 0.f, a3 = 0.f;
  float a4 = 0.f, a5 = 0.f, a6 = 0.f, a7 = 0.f;
  const size_t loff = (size_t)lane * 8;

  auto gat = [&](int c) -> uint4 {
    return *(const uint4*)(X + (size_t)c * WIDTH + loff);
  };
  auto fma1 = [&](float v, uint4 w) {
    a0 = fmaf(v, bf_lo(w.x), a0); a1 = fmaf(v, bf_hi(w.x), a1);
    a2 = fmaf(v, bf_lo(w.y), a2); a3 = fmaf(v, bf_hi(w.y), a3);
    a4 = fmaf(v, bf_lo(w.z), a4); a5 = fmaf(v, bf_hi(w.z), a5);
    a6 = fmaf(v, bf_lo(w.w), a6); a7 = fmaf(v, bf_hi(w.w), a7);
  };
  auto accum = [&](int c, float v) { fma1(v, gat(c)); };

  int e = e0;
  int epro = (e0 + 3) & ~3;             // align to 4 for vector col/val loads
  if (epro > e1) epro = e1;
  for (; e < epro; ++e)
    accum(__builtin_nontemporal_load(col + e),
          __builtin_nontemporal_load(val + e));

  int nb = (e1 - e) >> 2;               // full 4-edge batches
  if (nb > 0) {
    intx4 cA = __builtin_nontemporal_load((const intx4*)(col + e));
    fltx4 vA = __builtin_nontemporal_load((const fltx4*)(val + e));
    intx4 cB = cA; fltx4 vB = vA;
    if (nb > 1) {
      cB = __builtin_nontemporal_load((const intx4*)(col + e + 4));
      vB = __builtin_nontemporal_load((const fltx4*)(val + e + 4));
    }
    uint4 w0 = gat(cA.x), w1 = gat(cA.y), w2 = gat(cA.z), w3 = gat(cA.w);
    for (int t = 0; t < nb - 1; ++t) {
      intx4 cC = cB; fltx4 vC = vB;
      if (t + 2 < nb) {
        cC = __builtin_nontemporal_load((const intx4*)(col + e + 4 * (t + 2)));
        vC = __builtin_nontemporal_load((const fltx4*)(val + e + 4 * (t + 2)));
      }
      uint4 u0 = gat(cB.x), u1 = gat(cB.y), u2 = gat(cB.z), u3 = gat(cB.w);
      fma1(vA.x, w0); fma1(vA.y, w1); fma1(vA.z, w2); fma1(vA.w, w3);
      vA = vB; vB = vC; cB = cC;
      w0 = u0; w1 = u1; w2 = u2; w3 = u3;
    }
    fma1(vA.x, w0); fma1(vA.y, w1); fma1(vA.z, w2); fma1(vA.w, w3);
    e += nb * 4;
  }
  for (; e < e1; ++e)
    accum(__builtin_nontemporal_load(col + e),
          __builtin_nontemporal_load(val + e));

  if (OUTF32) {
    float* Y = (float*)Yv;
    fltx4 o0; o0.x = a0; o0.y = a1; o0.z = a2; o0.w = a3;
    fltx4 o1; o1.x = a4; o1.y = a5; o1.z = a6; o1.w = a7;
    __builtin_nontemporal_store(o0, (fltx4*)(Y + (size_t)g * WIDTH + lane * 8));
    __builtin_nontemporal_store(o1, (fltx4*)(Y + (size_t)g * WIDTH + lane * 8 + 4));
  } else {
    uintx4 o;
    o.x = pack2(a0, a1); o.y = pack2(a2, a3);
    o.z = pack2(a4, a5); o.w = pack2(a6, a7);
    __builtin_nontemporal_store(
        o, (uintx4*)((unsigned short*)Yv + (size_t)g * WIDTH + loff));
  }
}

// y=0: graph a, Xa->Ya; y=1: graph b, Xb->Yb (both 128-wide, bf16 out)
__global__ __launch_bounds__(256) void spmm_dual128_kernel(
    const int* __restrict__ rpa, const int* __restrict__ cola,
    const float* __restrict__ vala, const unsigned short* __restrict__ Xa,
    unsigned short* __restrict__ Ya,
    const int* __restrict__ rpb, const int* __restrict__ colb,
    const float* __restrict__ valb, const unsigned short* __restrict__ Xb,
    unsigned short* __restrict__ Yb, int n)
{
  if (blockIdx.y == 0)
    spmm_rows<128, false>(rpa, cola, vala, Xa, Ya, n, blockIdx.x);
  else
    spmm_rows<128, false>(rpb, colb, valb, Xb, Yb, n, blockIdx.x);
}

// y=0: graph b 128-wide D->Yb (bf16); y=1: graph a 64-wide Q->Pout (f32)
__global__ __launch_bounds__(256) void spmm_mixed_kernel(
    const int* __restrict__ rpb, const int* __restrict__ colb,
    const float* __restrict__ valb, const unsigned short* __restrict__ D,
    unsigned short* __restrict__ Yb,
    const int* __restrict__ rpa, const int* __restrict__ cola,
    const float* __restrict__ vala, const unsigned short* __restrict__ Q,
    float* __restrict__ Pout, int n)
{
  if (blockIdx.y == 0)
    spmm_rows<128, false>(rpb, colb, valb, D, Yb, n, blockIdx.x);
  else
    spmm_rows<64, true>(rpa, cola, vala, Q, Pout, n, blockIdx.x);
}

// ---------------------------------------------------------------------------
// GEMM building blocks (v9 verbatim). Block: 256 thr = 4 waves 2x2;
// tile 128 rows x HOUT. X operand in LDS; W fragments from global.
// ---------------------------------------------------------------------------
__device__ inline void stage_bf16(const unsigned short* __restrict__ Xp,
                                  unsigned short* Xs, int row0, int n,
                                  int rloc, int c8)
{
#pragma unroll
  for (int p = 0; p < 8; ++p) {
    int r = p * 16 + rloc;
    int gr = row0 + r;
    uint4 v = make_uint4(0u, 0u, 0u, 0u);
    if (gr < n) v = *(const uint4*)(Xp + (size_t)gr * 128 + c8);
    *(uint4*)(Xs + r * LDXP + c8) = v;
  }
}

template <int NT>
__device__ inline void mfma_phase(const unsigned short* __restrict__ W, int wld,
                                  const unsigned short* Xs,
                                  int wm, int wn, int l15, int quad,
                                  floatx4 (&acc)[4][NT])
{
#pragma unroll
  for (int k0 = 0; k0 < 128; k0 += 32) {
    const int ko = k0 + quad * 8;
    short8 aW[NT], bX[4];
#pragma unroll
    for (int j = 0; j < NT; ++j)
      aW[j] = *(const short8*)(W + (size_t)(wn * (16 * NT) + j * 16 + l15) * wld + ko);
#pragma unroll
    for (int i = 0; i < 4; ++i)
      bX[i] = *(const short8*)(Xs + (wm * 64 + i * 16 + l15) * LDXP + ko);
#pragma unroll
    for (int i = 0; i < 4; ++i)
#pragma unroll
      for (int j = 0; j < NT; ++j)
        acc[i][j] = __builtin_amdgcn_mfma_f32_16x16x32_bf16(aW[j], bX[i], acc[i][j], 0, 0, 0);
  }
}

// A = relu(x@W1.T+b1), C = relu(x@W2.T+b2) from fp32 x, shared X staging.
__global__ __launch_bounds__(256, 2) void gemm_dual_f32_kernel(
    const float* __restrict__ X, const unsigned short* __restrict__ W1,
    const unsigned short* __restrict__ W2, const float* __restrict__ b1,
    const float* __restrict__ b2, unsigned short* __restrict__ Y1,
    unsigned short* __restrict__ Y2, int n)
{
  constexpr int NT = 4;  // HOUT = 128
  __shared__ unsigned short Xs[128 * LDXP];
  const int tid = threadIdx.x;
  const int lane = tid & 63;
  const int wave = tid >> 6;
  const int wm = wave >> 1;
  const int wn = wave & 1;
  const int l15 = lane & 15;
  const int quad = lane >> 4;
  const int row0 = blockIdx.x * 128;
  const int c8 = (tid & 15) * 8;
  const int rloc = tid >> 4;

#pragma unroll
  for (int p = 0; p < 8; ++p) {
    int r = p * 16 + rloc;
    int gr = row0 + r;
    uint4 o = make_uint4(0u, 0u, 0u, 0u);
    if (gr < n) {
      float4 f0 = *(const float4*)(X + (size_t)gr * 128 + c8);
      float4 f1 = *(const float4*)(X + (size_t)gr * 128 + c8 + 4);
      o.x = pack2(f0.x, f0.y); o.y = pack2(f0.z, f0.w);
      o.z = pack2(f1.x, f1.y); o.w = pack2(f1.z, f1.w);
    }
    *(uint4*)(Xs + r * LDXP + c8) = o;
  }
  __syncthreads();

  for (int s = 0; s < 2; ++s) {
    const unsigned short* W = s ? W2 : W1;
    const float* b = s ? b2 : b1;
    unsigned short* Y = s ? Y2 : Y1;
    floatx4 acc[4][NT];
#pragma unroll
    for (int i = 0; i < 4; ++i)
#pragma unroll
      for (int j = 0; j < NT; ++j) acc[i][j] = (floatx4){0.f, 0.f, 0.f, 0.f};
    mfma_phase<NT>(W, 128, Xs, wm, wn, l15, quad, acc);
#pragma unroll
    for (int i = 0; i < 4; ++i) {
      int r = row0 + wm * 64 + i * 16 + l15;
      if (r >= n) continue;
#pragma unroll
      for (int j = 0; j < NT; ++j) {
        int c0 = wn * 64 + j * 16 + quad * 4;
        float4 bb = *(const float4*)(b + c0);
        float v0 = fmaxf(acc[i][j][0] + bb.x, 0.f);
        float v1 = fmaxf(acc[i][j][1] + bb.y, 0.f);
        float v2 = fmaxf(acc[i][j][2] + bb.z, 0.f);
        float v3 = fmaxf(acc[i][j][3] + bb.w, 0.f);
        uint2 o; o.x = pack2(v0, v1); o.y = pack2(v2, v3);
        *(uint2*)(Y + (size_t)r * 128 + c0) = o;
      }
    }
  }
}

// y=0: Q = (relu(B·Wa1^T+ba1))·Wo0^T (chained through LDS)
// y=1: D = relu(B2·Wb1^T+bb1)
__global__ __launch_bounds__(256, 2) void chain_g1_kernel(
    const unsigned short* __restrict__ B, const unsigned short* __restrict__ Wa1,
    const float* __restrict__ ba1, const unsigned short* __restrict__ Wo0,
    unsigned short* __restrict__ Q,
    const unsigned short* __restrict__ B2, const unsigned short* __restrict__ Wb1,
    const float* __restrict__ bb1, unsigned short* __restrict__ D, int n)
{
  __shared__ unsigned short Xs[128 * LDXP];
  const int tid = threadIdx.x;
  const int lane = tid & 63;
  const int wave = tid >> 6;
  const int wm = wave >> 1;
  const int wn = wave & 1;
  const int l15 = lane & 15;
  const int quad = lane >> 4;
  const int row0 = blockIdx.x * 128;
  const int c8 = (tid & 15) * 8;
  const int rloc = tid >> 4;

  if (blockIdx.y == 0) {
    stage_bf16(B, Xs, row0, n, rloc, c8);
    __syncthreads();

    floatx4 acc1[4][4];
#pragma unroll
    for (int i = 0; i < 4; ++i)
#pragma unroll
      for (int j = 0; j < 4; ++j) acc1[i][j] = (floatx4){0.f, 0.f, 0.f, 0.f};
    mfma_phase<4>(Wa1, 128, Xs, wm, wn, l15, quad, acc1);
    __syncthreads();   // all stage-1 reads of Xs done before overwrite

    // A2 = relu(acc1 + ba1) -> Xs (bf16)
#pragma unroll
    for (int i = 0; i < 4; ++i) {
      int r2 = wm * 64 + i * 16 + l15;
#pragma unroll
      for (int j = 0; j < 4; ++j) {
        int c2 = wn * 64 + j * 16 + quad * 4;
        float4 bb = *(const float4*)(ba1 + c2);
        float v0 = fmaxf(acc1[i][j][0] + bb.x, 0.f);
        float v1 = fmaxf(acc1[i][j][1] + bb.y, 0.f);
        float v2 = fmaxf(acc1[i][j][2] + bb.z, 0.f);
        float v3 = fmaxf(acc1[i][j][3] + bb.w, 0.f);
        uint2 o; o.x = pack2(v0, v1); o.y = pack2(v2, v3);
        *(uint2*)(Xs + r2 * LDXP + c2) = o;
      }
    }
    __syncthreads();

    floatx4 acc2[4][2];
#pragma unroll
    for (int i = 0; i < 4; ++i)
#pragma unroll
      for (int j = 0; j < 2; ++j) acc2[i][j] = (floatx4){0.f, 0.f, 0.f, 0.f};
    mfma_phase<2>(Wo0, 128, Xs, wm, wn, l15, quad, acc2);

#pragma unroll
    for (int i = 0; i < 4; ++i) {
      int r = row0 + wm * 64 + i * 16 + l15;
      if (r >= n) continue;
#pragma unroll
      for (int j = 0; j < 2; ++j) {
        int c0 = wn * 32 + j * 16 + quad * 4;
        uint2 o;
        o.x = pack2(acc2[i][j][0], acc2[i][j][1]);
        o.y = pack2(acc2[i][j][2], acc2[i][j][3]);
        *(uint2*)(Q + (size_t)r * 64 + c0) = o;
      }
    }
  } else {
    stage_bf16(B2, Xs, row0, n, rloc, c8);
    __syncthreads();

    floatx4 acc[4][4];
#pragma unroll
    for (int i = 0; i < 4; ++i)
#pragma unroll
      for (int j = 0; j < 4; ++j) acc[i][j] = (floatx4){0.f, 0.f, 0.f, 0.f};
    mfma_phase<4>(Wb1, 128, Xs, wm, wn, l15, quad, acc);

#pragma unroll
    for (int i = 0; i < 4; ++i) {
      int r = row0 + wm * 64 + i * 16 + l15;
      if (r >= n) continue;
#pragma unroll
      for (int j = 0; j < 4; ++j) {
        int c0 = wn * 64 + j * 16 + quad * 4;
        float4 bb = *(const float4*)(bb1 + c0);
        float v0 = fmaxf(acc[i][j][0] + bb.x, 0.f);
        float v1 = fmaxf(acc[i][j][1] + bb.y, 0.f);
        float v2 = fmaxf(acc[i][j][2] + bb.z, 0.f);
        float v3 = fmaxf(acc[i][j][3] + bb.w, 0.f);
        uint2 o; o.x = pack2(v0, v1); o.y = pack2(v2, v3);
        *(uint2*)(D + (size_t)r * 128 + c0) = o;
      }
    }
  }
}

// out = relu(C·Wm0 + D·Wm1 + G2·Wm2 + bm)·Wo1^T + bo + Pout  (A3 in LDS only)
__global__ __launch_bounds__(256, 2) void wm_final_kernel(
    const unsigned short* __restrict__ C, const unsigned short* __restrict__ D,
    const unsigned short* __restrict__ G2,
    const unsigned short* __restrict__ Wm, const float* __restrict__ bm,
    const unsigned short* __restrict__ Wo1, const float* __restrict__ bo,
    const float* __restrict__ Pout, float* __restrict__ out, int n)
{
  __shared__ unsigned short Xs[128 * LDXP];
  const int tid = threadIdx.x;
  const int lane = tid & 63;
  const int wave = tid >> 6;
  const int wm_ = wave >> 1;
  const int wn = wave & 1;
  const int l15 = lane & 15;
  const int quad = lane >> 4;
  const int row0 = blockIdx.x * 128;
  const int c8 = (tid & 15) * 8;
  const int rloc = tid >> 4;

  floatx4 acc[4][4];
#pragma unroll
  for (int i = 0; i < 4; ++i)
#pragma unroll
    for (int j = 0; j < 4; ++j) acc[i][j] = (floatx4){0.f, 0.f, 0.f, 0.f};

  const unsigned short* Xp[3] = {C, D, G2};
#pragma unroll
  for (int s = 0; s < 3; ++s) {
    if (s) __syncthreads();
    stage_bf16(Xp[s], Xs, row0, n, rloc, c8);
    __syncthreads();
    mfma_phase<4>(Wm + s * 128, 384, Xs, wm_, wn, l15, quad, acc);
  }
  __syncthreads();   // all K=384 reads done before A3 overwrite

  // A3 = relu(acc + bm) -> Xs (bf16)
#pragma unroll
  for (int i = 0; i < 4; ++i) {
    int r2 = wm_ * 64 + i * 16 + l15;
#pragma unroll
    for (int j = 0; j < 4; ++j) {
      int c2 = wn * 64 + j * 16 + quad * 4;
      float4 bb = *(const float4*)(bm + c2);
      float v0 = fmaxf(acc[i][j][0] + bb.x, 0.f);
      float v1 = fmaxf(acc[i][j][1] + bb.y, 0.f);
      float v2 = fmaxf(acc[i][j][2] + bb.z, 0.f);
      float v3 = fmaxf(acc[i][j][3] + bb.w, 0.f);
      uint2 o; o.x = pack2(v0, v1); o.y = pack2(v2, v3);
      *(uint2*)(Xs + r2 * LDXP + c2) = o;
    }
  }
  __syncthreads();

  floatx4 acc2[4][2];
#pragma unroll
  for (int i = 0; i < 4; ++i)
#pragma unroll
    for (int j = 0; j < 2; ++j) acc2[i][j] = (floatx4){0.f, 0.f, 0.f, 0.f};
  mfma_phase<2>(Wo1, 128, Xs, wm_, wn, l15, quad, acc2);

#pragma unroll
  for (int i = 0; i < 4; ++i) {
    int r = row0 + wm_ * 64 + i * 16 + l15;
    if (r >= n) continue;
#pragma unroll
    for (int j = 0; j < 2; ++j) {
      int c0 = wn * 32 + j * 16 + quad * 4;
      float4 bb = *(const float4*)(bo + c0);
      float4 pv = *(const float4*)(Pout + (size_t)r * 64 + c0);
      float4 o;
      o.x = acc2[i][j][0] + bb.x + pv.x;
      o.y = acc2[i][j][1] + bb.y + pv.y;
      o.z = acc2[i][j][2] + bb.z + pv.z;
      o.w = acc2[i][j][3] + bb.w + pv.w;
      *(float4*)(out + (size_t)r * 64 + c0) = o;
    }
  }
}

extern "C" void kernel_launch(void* const* d_in, const int* in_sizes, int n_in,
                              void* d_out, int out_size, void* d_ws, size_t ws_size,
                              hipStream_t stream)
{
  const float* x     = (const float*)d_in[0];
  const int*   row_a = (const int*)d_in[1];
  const int*   col_a = (const int*)d_in[2];
  const float* val_a = (const float*)d_in[3];
  const int*   row_b = (const int*)d_in[4];
  const int*   col_b = (const int*)d_in[5];
  const float* val_b = (const float*)d_in[6];
  const float* Wa0 = (const float*)d_in[7];  const float* ba0 = (const float*)d_in[8];
  const float* Wa1 = (const float*)d_in[9];  const float* ba1 = (const float*)d_in[10];
  const float* Wb0 = (const float*)d_in[11]; const float* bb0 = (const float*)d_in[12];
  const float* Wb1 = (const float*)d_in[13]; const float* bb1 = (const float*)d_in[14];
  const float* Wm  = (const float*)d_in[15]; const float* bm  = (const float*)d_in[16];
  const float* Wo  = (const float*)d_in[17]; const float* bo  = (const float*)d_in[18];
  float* out = (float*)d_out;

  const int n = in_sizes[0] / 128;   // 50000
  const int E = in_sizes[1];         // 800000

  char* ws = (char*)d_ws;
  size_t off = 0;
  auto alloc = [&](size_t bytes) {
    void* p = ws + off;
    off = (off + bytes + 255) & ~(size_t)255;
    return p;
  };
  int* rpa = (int*)alloc((size_t)(n + 1) * sizeof(int));
  int* rpb = (int*)alloc((size_t)(n + 1) * sizeof(int));
  unsigned short* Wcat = (unsigned short*)alloc(131072 * sizeof(unsigned short));
  const size_t slab = (size_t)n * 128 * sizeof(unsigned short);
  unsigned short* A  = (unsigned short*)alloc(slab);   // relu(x Wa0 + ba0)
  unsigned short* C  = (unsigned short*)alloc(slab);   // g0
  unsigned short* B  = (unsigned short*)alloc(slab);   // graph-a sp1 out / g2
  unsigned short* B2 = (unsigned short*)alloc(slab);   // graph-b sp1 out
  unsigned short* D  = (unsigned short*)alloc(slab);   // g1
  unsigned short* Q  = (unsigned short*)alloc((size_t)n * 64 * sizeof(unsigned short));
  float* Pout = (float*)alloc((size_t)n * 64 * sizeof(float)); // x_a @ Wo0^T

  const unsigned short* Wa0b = Wcat;
  const unsigned short* Wa1b = Wcat + 16384;
  const unsigned short* Wb0b = Wcat + 32768;
  const unsigned short* Wb1b = Wcat + 49152;
  const unsigned short* Wmb  = Wcat + 65536;   // [128, 384]
  const unsigned short* Wo0b = Wcat + 114688;
  const unsigned short* Wo1b = Wcat + 122880;

  dim3 blk(256);
  dim3 g_setup((n + 1 + 255) / 256, 3);
  dim3 g_lin((n + 127) / 128);
  dim3 g_cg((n + 127) / 128, 2);
  dim3 g_sp2((n + 15) / 16, 2);

  setup_kernel<<<g_setup, blk, 0, stream>>>(row_a, row_b, E, n, rpa, rpb,
                                            Wa0, Wa1, Wb0, Wb1, Wm, Wo, Wcat);

  // A = relu(x Wa0^T + ba0), C = relu(x Wb0^T + bb0)
  gemm_dual_f32_kernel<<<g_lin, blk, 0, stream>>>(x, Wa0b, Wb0b, ba0, bb0, A, C, n);

  // spmm_a(A->B) || spmm_b(C->B2)
  spmm_dual128_kernel<<<g_sp2, blk, 0, stream>>>(
      rpa, col_a, val_a, A, B,
      rpb, col_b, val_b, C, B2, n);

  // chain: Q = relu(B Wa1^T + ba1) Wo0^T  ||  g1: D = relu(B2 Wb1^T + bb1)
  chain_g1_kernel<<<g_cg, blk, 0, stream>>>(
      B, Wa1b, ba1, Wo0b, Q,
      B2, Wb1b, bb1, D, n);

  // g2 = spmm_b(D) -> B  ||  Pout = spmm_a(Q)
  spmm_mixed_kernel<<<g_sp2, blk, 0, stream>>>(
      rpb, col_b, val_b, D, B,
      rpa, col_a, val_a, Q, Pout, n);

  // out = relu(g0 Wm0 + g1 Wm1 + g2 Wm2 + bm) Wo1^T + bo + Pout
  wm_final_kernel<<<g_lin, blk, 0, stream>>>(
      C, D, B, Wmb, bm, Wo1b, bo, Pout, out, n);
}

// Round 11
// 279.916 us; speedup vs baseline: 1.2565x; 1.1465x over previous
//
#include <hip/hip_runtime.h>

// ---------------------------------------------------------------------------
// DualGCN v13: v9 structure (best, 292.6us) + fp8-e4m3 gather slabs.
//   Every SpMM gather input gets an fp8 copy written by its producer GEMM
//   (HW v_cvt_pk_fp8_f32 encode / v_cvt_pk_f32_fp8 decode — self-consistent).
//   128-wide fp8 row = 128 B = ONE cache line (vs 2 for bf16): per-edge line
//   fetches halve and slab footprint halves (6.4 MB -> L2-resident-ish).
//   GEMM operands stay bf16 (C, D, B, B2); A and Q are spmm-only -> fp8 only.
//   SpMM kernel: v5/v9 depth-2 pipeline, uint2 (8B) gathers + fp8 decode.
// 6 launches. N=50000, E=800000, H=128, OUT=64.
// ---------------------------------------------------------------------------

typedef short short8 __attribute__((ext_vector_type(8)));
typedef float floatx4 __attribute__((ext_vector_type(4)));
typedef float floatx2 __attribute__((ext_vector_type(2)));

#define LDXP 136   // padded LDS row stride (bf16 units)

__device__ inline unsigned short f2bf(float f) {
  unsigned u = __builtin_bit_cast(unsigned, f);
  u += 0x7fffu + ((u >> 16) & 1u);      // round-to-nearest-even
  return (unsigned short)(u >> 16);
}
__device__ inline unsigned pack2(float a, float b) {
  return (unsigned)f2bf(a) | ((unsigned)f2bf(b) << 16);
}
__device__ inline float bf_lo(unsigned w) {
  return __builtin_bit_cast(float, w << 16);
}
__device__ inline float bf_hi(unsigned w) {
  return __builtin_bit_cast(float, w & 0xffff0000u);
}
// 4 floats -> 4 fp8 bytes (RNE, HW)
__device__ inline unsigned pack_fp8x4(float v0, float v1, float v2, float v3) {
  int p = 0;
  p = __builtin_amdgcn_cvt_pk_fp8_f32(v0, v1, p, false);   // bytes 0,1
  p = __builtin_amdgcn_cvt_pk_fp8_f32(v2, v3, p, true);    // bytes 2,3
  return (unsigned)p;
}

// y=0: rowptr for graph a; y=1: rowptr for graph b; y=2: convert weights.
// Wo de-interleaved into Wo0 = Wo[:, :128] and Wo1 = Wo[:, 128:].
__global__ __launch_bounds__(256) void setup_kernel(
    const int* __restrict__ rowA, const int* __restrict__ rowB,
    int E, int n, int* __restrict__ rpa, int* __restrict__ rpb,
    const float* __restrict__ Wa0, const float* __restrict__ Wa1,
    const float* __restrict__ Wb0, const float* __restrict__ Wb1,
    const float* __restrict__ Wm,  const float* __restrict__ Wo,
    unsigned short* __restrict__ Wout)
{
  if (blockIdx.y == 2) {
    for (int i = blockIdx.x * 256 + threadIdx.x; i < 131072; i += gridDim.x * 256) {
      float v;
      if      (i < 16384)  v = Wa0[i];
      else if (i < 32768)  v = Wa1[i - 16384];
      else if (i < 49152)  v = Wb0[i - 32768];
      else if (i < 65536)  v = Wb1[i - 49152];
      else if (i < 114688) v = Wm[i - 65536];
      else {
        int o = i - 114688;           // [0, 16384)
        int half = o >> 13;           // 0 -> Wo0, 1 -> Wo1
        int idx = o & 8191;
        int r = idx >> 7, c = idx & 127;
        v = Wo[r * 256 + half * 128 + c];
      }
      Wout[i] = f2bf(v);
    }
    return;
  }
  int i = blockIdx.x * blockDim.x + threadIdx.x;
  if (i > n) return;
  const int* row = blockIdx.y ? rowB : rowA;
  int* rp = blockIdx.y ? rpb : rpa;
  int lo = 0, hi = E;
  while (lo < hi) {
    int mid = (lo + hi) >> 1;
    if (row[mid] < i) lo = mid + 1; else hi = mid;
  }
  rp[i] = lo;
}

// ---------------------------------------------------------------------------
// SpMM row body, fp8 gathers (v5 depth-2 pipeline):
// Y[g,:] = sum_e val[e] * X8[col[e],:]   (X8 fp8-e4m3, WIDTH features)
// WIDTH/8 lanes per row, 8 B (8 fp8) gather per lane, decode via HW cvt.
// ---------------------------------------------------------------------------
template <int WIDTH, bool OUTF32>
__device__ __forceinline__ void spmm_rows_fp8(
    const int* __restrict__ rowptr, const int* __restrict__ col,
    const float* __restrict__ val, const unsigned char* __restrict__ X8,
    void* __restrict__ Yv, int n, int bx)
{
  constexpr int LPR = WIDTH / 8;        // lanes per row
  constexpr int GPB = 256 / LPR;        // row-groups per block
  int g = bx * GPB + ((int)threadIdx.x / LPR);
  int lane = threadIdx.x & (LPR - 1);
  if (g >= n) return;
  int e0 = rowptr[g], e1 = rowptr[g + 1];

  float a0 = 0.f, a1 = 0.f, a2 = 0.f, a3 = 0.f;
  float a4 = 0.f, a5 = 0.f, a6 = 0.f, a7 = 0.f;
  const size_t loff = (size_t)lane * 8;

  auto gat = [&](int c) -> uint2 {
    return *(const uint2*)(X8 + (size_t)c * WIDTH + loff);
  };
  auto fma1 = [&](float v, uint2 w) {
    floatx2 p;
    p = __builtin_amdgcn_cvt_pk_f32_fp8((int)w.x, false);
    a0 = fmaf(v, p.x, a0); a1 = fmaf(v, p.y, a1);
    p = __builtin_amdgcn_cvt_pk_f32_fp8((int)w.x, true);
    a2 = fmaf(v, p.x, a2); a3 = fmaf(v, p.y, a3);
    p = __builtin_amdgcn_cvt_pk_f32_fp8((int)w.y, false);
    a4 = fmaf(v, p.x, a4); a5 = fmaf(v, p.y, a5);
    p = __builtin_amdgcn_cvt_pk_f32_fp8((int)w.y, true);
    a6 = fmaf(v, p.x, a6); a7 = fmaf(v, p.y, a7);
  };
  auto accum = [&](int c, float v) { fma1(v, gat(c)); };

  int e = e0;
  int epro = (e0 + 3) & ~3;             // align to 4 for vector col/val loads
  if (epro > e1) epro = e1;
  for (; e < epro; ++e) accum(col[e], val[e]);

  int nb = (e1 - e) >> 2;               // full 4-edge batches
  if (nb > 0) {
    int4   cA = *(const int4*)(col + e);
    float4 vA = *(const float4*)(val + e);
    int4   cB = cA; float4 vB = vA;
    if (nb > 1) { cB = *(const int4*)(col + e + 4); vB = *(const float4*)(val + e + 4); }
    uint2 w0 = gat(cA.x), w1 = gat(cA.y), w2 = gat(cA.z), w3 = gat(cA.w);
    for (int t = 0; t < nb - 1; ++t) {
      int4 cC = cB; float4 vC = vB;
      if (t + 2 < nb) {
        cC = *(const int4*)(col + e + 4 * (t + 2));
        vC = *(const float4*)(val + e + 4 * (t + 2));
      }
      uint2 u0 = gat(cB.x), u1 = gat(cB.y), u2 = gat(cB.z), u3 = gat(cB.w);
      fma1(vA.x, w0); fma1(vA.y, w1); fma1(vA.z, w2); fma1(vA.w, w3);
      vA = vB; vB = vC; cB = cC;
      w0 = u0; w1 = u1; w2 = u2; w3 = u3;
    }
    fma1(vA.x, w0); fma1(vA.y, w1); fma1(vA.z, w2); fma1(vA.w, w3);
    e += nb * 4;
  }
  for (; e < e1; ++e) accum(col[e], val[e]);

  if (OUTF32) {
    float* Y = (float*)Yv;
    float4 o0; o0.x = a0; o0.y = a1; o0.z = a2; o0.w = a3;
    float4 o1; o1.x = a4; o1.y = a5; o1.z = a6; o1.w = a7;
    *(float4*)(Y + (size_t)g * WIDTH + lane * 8) = o0;
    *(float4*)(Y + (size_t)g * WIDTH + lane * 8 + 4) = o1;
  } else {
    uint4 o;
    o.x = pack2(a0, a1); o.y = pack2(a2, a3);
    o.z = pack2(a4, a5); o.w = pack2(a6, a7);
    *(uint4*)((unsigned short*)Yv + (size_t)g * WIDTH + loff) = o;
  }
}

// y=0: graph a, A8->B; y=1: graph b, C8->B2 (both 128-wide fp8 in, bf16 out)
__global__ __launch_bounds__(256) void spmm_dual128_kernel(
    const int* __restrict__ rpa, const int* __restrict__ cola,
    const float* __restrict__ vala, const unsigned char* __restrict__ A8,
    unsigned short* __restrict__ B,
    const int* __restrict__ rpb, const int* __restrict__ colb,
    const float* __restrict__ valb, const unsigned char* __restrict__ C8,
    unsigned short* __restrict__ B2, int n)
{
  if (blockIdx.y == 0)
    spmm_rows_fp8<128, false>(rpa, cola, vala, A8, B, n, blockIdx.x);
  else
    spmm_rows_fp8<128, false>(rpb, colb, valb, C8, B2, n, blockIdx.x);
}

// y=0: graph b 128-wide D8->Yb (bf16); y=1: graph a 64-wide Q8->Pout (f32)
__global__ __launch_bounds__(256) void spmm_mixed_kernel(
    const int* __restrict__ rpb, const int* __restrict__ colb,
    const float* __restrict__ valb, const unsigned char* __restrict__ D8,
    unsigned short* __restrict__ Yb,
    const int* __restrict__ rpa, const int* __restrict__ cola,
    const float* __restrict__ vala, const unsigned char* __restrict__ Q8,
    float* __restrict__ Pout, int n)
{
  if (blockIdx.y == 0)
    spmm_rows_fp8<128, false>(rpb, colb, valb, D8, Yb, n, blockIdx.x);
  else
    spmm_rows_fp8<64, true>(rpa, cola, vala, Q8, Pout, n, blockIdx.x);
}

// ---------------------------------------------------------------------------
// GEMM building blocks (v9 verbatim). Block: 256 thr = 4 waves 2x2;
// tile 128 rows x HOUT. X operand in LDS; W fragments from global.
// ---------------------------------------------------------------------------
__device__ inline void stage_bf16(const unsigned short* __restrict__ Xp,
                                  unsigned short* Xs, int row0, int n,
                                  int rloc, int c8)
{
#pragma unroll
  for (int p = 0; p < 8; ++p) {
    int r = p * 16 + rloc;
    int gr = row0 + r;
    uint4 v = make_uint4(0u, 0u, 0u, 0u);
    if (gr < n) v = *(const uint4*)(Xp + (size_t)gr * 128 + c8);
    *(uint4*)(Xs + r * LDXP + c8) = v;
  }
}

template <int NT>
__device__ inline void mfma_phase(const unsigned short* __restrict__ W, int wld,
                                  const unsigned short* Xs,
                                  int wm, int wn, int l15, int quad,
                                  floatx4 (&acc)[4][NT])
{
#pragma unroll
  for (int k0 = 0; k0 < 128; k0 += 32) {
    const int ko = k0 + quad * 8;
    short8 aW[NT], bX[4];
#pragma unroll
    for (int j = 0; j < NT; ++j)
      aW[j] = *(const short8*)(W + (size_t)(wn * (16 * NT) + j * 16 + l15) * wld + ko);
#pragma unroll
    for (int i = 0; i < 4; ++i)
      bX[i] = *(const short8*)(Xs + (wm * 64 + i * 16 + l15) * LDXP + ko);
#pragma unroll
    for (int i = 0; i < 4; ++i)
#pragma unroll
      for (int j = 0; j < NT; ++j)
        acc[i][j] = __builtin_amdgcn_mfma_f32_16x16x32_bf16(aW[j], bX[i], acc[i][j], 0, 0, 0);
  }
}

// A8 = fp8(relu(x@W1.T+b1)) [spmm-only], C = relu(x@W2.T+b2) bf16 + C8 fp8.
__global__ __launch_bounds__(256, 2) void gemm_dual_f32_kernel(
    const float* __restrict__ X, const unsigned short* __restrict__ W1,
    const unsigned short* __restrict__ W2, const float* __restrict__ b1,
    const float* __restrict__ b2, unsigned char* __restrict__ A8,
    unsigned short* __restrict__ C, unsigned char* __restrict__ C8, int n)
{
  constexpr int NT = 4;  // HOUT = 128
  __shared__ unsigned short Xs[128 * LDXP];
  const int tid = threadIdx.x;
  const int lane = tid & 63;
  const int wave = tid >> 6;
  const int wm = wave >> 1;
  const int wn = wave & 1;
  const int l15 = lane & 15;
  const int quad = lane >> 4;
  const int row0 = blockIdx.x * 128;
  const int c8 = (tid & 15) * 8;
  const int rloc = tid >> 4;

#pragma unroll
  for (int p = 0; p < 8; ++p) {
    int r = p * 16 + rloc;
    int gr = row0 + r;
    uint4 o = make_uint4(0u, 0u, 0u, 0u);
    if (gr < n) {
      float4 f0 = *(const float4*)(X + (size_t)gr * 128 + c8);
      float4 f1 = *(const float4*)(X + (size_t)gr * 128 + c8 + 4);
      o.x = pack2(f0.x, f0.y); o.y = pack2(f0.z, f0.w);
      o.z = pack2(f1.x, f1.y); o.w = pack2(f1.z, f1.w);
    }
    *(uint4*)(Xs + r * LDXP + c8) = o;
  }
  __syncthreads();

  for (int s = 0; s < 2; ++s) {
    const unsigned short* W = s ? W2 : W1;
    const float* b = s ? b2 : b1;
    floatx4 acc[4][NT];
#pragma unroll
    for (int i = 0; i < 4; ++i)
#pragma unroll
      for (int j = 0; j < NT; ++j) acc[i][j] = (floatx4){0.f, 0.f, 0.f, 0.f};
    mfma_phase<NT>(W, 128, Xs, wm, wn, l15, quad, acc);
#pragma unroll
    for (int i = 0; i < 4; ++i) {
      int r = row0 + wm * 64 + i * 16 + l15;
      if (r >= n) continue;
#pragma unroll
      for (int j = 0; j < NT; ++j) {
        int c0 = wn * 64 + j * 16 + quad * 4;
        float4 bb = *(const float4*)(b + c0);
        float v0 = fmaxf(acc[i][j][0] + bb.x, 0.f);
        float v1 = fmaxf(acc[i][j][1] + bb.y, 0.f);
        float v2 = fmaxf(acc[i][j][2] + bb.z, 0.f);
        float v3 = fmaxf(acc[i][j][3] + bb.w, 0.f);
        unsigned p8 = pack_fp8x4(v0, v1, v2, v3);
        if (s == 0) {
          *(unsigned*)(A8 + (size_t)r * 128 + c0) = p8;      // A: fp8 only
        } else {
          uint2 o; o.x = pack2(v0, v1); o.y = pack2(v2, v3);
          *(uint2*)(C + (size_t)r * 128 + c0) = o;           // C: bf16 (GEMM)
          *(unsigned*)(C8 + (size_t)r * 128 + c0) = p8;      // C: fp8 (spmm)
        }
      }
    }
  }
}

// y=0: Q8 = fp8((relu(B·Wa1^T+ba1))·Wo0^T) (chained through LDS, spmm-only)
// y=1: D = relu(B2·Wb1^T+bb1) bf16 + D8 fp8
__global__ __launch_bounds__(256, 2) void chain_g1_kernel(
    const unsigned short* __restrict__ B, const unsigned short* __restrict__ Wa1,
    const float* __restrict__ ba1, const unsigned short* __restrict__ Wo0,
    unsigned char* __restrict__ Q8,
    const unsigned short* __restrict__ B2, const unsigned short* __restrict__ Wb1,
    const float* __restrict__ bb1, unsigned short* __restrict__ D,
    unsigned char* __restrict__ D8, int n)
{
  __shared__ unsigned short Xs[128 * LDXP];
  const int tid = threadIdx.x;
  const int lane = tid & 63;
  const int wave = tid >> 6;
  const int wm = wave >> 1;
  const int wn = wave & 1;
  const int l15 = lane & 15;
  const int quad = lane >> 4;
  const int row0 = blockIdx.x * 128;
  const int c8 = (tid & 15) * 8;
  const int rloc = tid >> 4;

  if (blockIdx.y == 0) {
    stage_bf16(B, Xs, row0, n, rloc, c8);
    __syncthreads();

    floatx4 acc1[4][4];
#pragma unroll
    for (int i = 0; i < 4; ++i)
#pragma unroll
      for (int j = 0; j < 4; ++j) acc1[i][j] = (floatx4){0.f, 0.f, 0.f, 0.f};
    mfma_phase<4>(Wa1, 128, Xs, wm, wn, l15, quad, acc1);
    __syncthreads();   // all stage-1 reads of Xs done before overwrite

    // A2 = relu(acc1 + ba1) -> Xs (bf16)
#pragma unroll
    for (int i = 0; i < 4; ++i) {
      int r2 = wm * 64 + i * 16 + l15;
#pragma unroll
      for (int j = 0; j < 4; ++j) {
        int c2 = wn * 64 + j * 16 + quad * 4;
        float4 bb = *(const float4*)(ba1 + c2);
        float v0 = fmaxf(acc1[i][j][0] + bb.x, 0.f);
        float v1 = fmaxf(acc1[i][j][1] + bb.y, 0.f);
        float v2 = fmaxf(acc1[i][j][2] + bb.z, 0.f);
        float v3 = fmaxf(acc1[i][j][3] + bb.w, 0.f);
        uint2 o; o.x = pack2(v0, v1); o.y = pack2(v2, v3);
        *(uint2*)(Xs + r2 * LDXP + c2) = o;
      }
    }
    __syncthreads();

    floatx4 acc2[4][2];
#pragma unroll
    for (int i = 0; i < 4; ++i)
#pragma unroll
      for (int j = 0; j < 2; ++j) acc2[i][j] = (floatx4){0.f, 0.f, 0.f, 0.f};
    mfma_phase<2>(Wo0, 128, Xs, wm, wn, l15, quad, acc2);

#pragma unroll
    for (int i = 0; i < 4; ++i) {
      int r = row0 + wm * 64 + i * 16 + l15;
      if (r >= n) continue;
#pragma unroll
      for (int j = 0; j < 2; ++j) {
        int c0 = wn * 32 + j * 16 + quad * 4;
        unsigned p8 = pack_fp8x4(acc2[i][j][0], acc2[i][j][1],
                                 acc2[i][j][2], acc2[i][j][3]);
        *(unsigned*)(Q8 + (size_t)r * 64 + c0) = p8;
      }
    }
  } else {
    stage_bf16(B2, Xs, row0, n, rloc, c8);
    __syncthreads();

    floatx4 acc[4][4];
#pragma unroll
    for (int i = 0; i < 4; ++i)
#pragma unroll
      for (int j = 0; j < 4; ++j) acc[i][j] = (floatx4){0.f, 0.f, 0.f, 0.f};
    mfma_phase<4>(Wb1, 128, Xs, wm, wn, l15, quad, acc);

#pragma unroll
    for (int i = 0; i < 4; ++i) {
      int r = row0 + wm * 64 + i * 16 + l15;
      if (r >= n) continue;
#pragma unroll
      for (int j = 0; j < 4; ++j) {
        int c0 = wn * 64 + j * 16 + quad * 4;
        float4 bb = *(const float4*)(bb1 + c0);
        float v0 = fmaxf(acc[i][j][0] + bb.x, 0.f);
        float v1 = fmaxf(acc[i][j][1] + bb.y, 0.f);
        float v2 = fmaxf(acc[i][j][2] + bb.z, 0.f);
        float v3 = fmaxf(acc[i][j][3] + bb.w, 0.f);
        uint2 o; o.x = pack2(v0, v1); o.y = pack2(v2, v3);
        *(uint2*)(D + (size_t)r * 128 + c0) = o;             // bf16 (GEMM)
        *(unsigned*)(D8 + (size_t)r * 128 + c0) = pack_fp8x4(v0, v1, v2, v3);
      }
    }
  }
}

// out = relu(C·Wm0 + D·Wm1 + G2·Wm2 + bm)·Wo1^T + bo + Pout  (A3 in LDS only)
__global__ __launch_bounds__(256, 2) void wm_final_kernel(
    const unsigned short* __restrict__ C, const unsigned short* __restrict__ D,
    const unsigned short* __restrict__ G2,
    const unsigned short* __restrict__ Wm, const float* __restrict__ bm,
    const unsigned short* __restrict__ Wo1, const float* __restrict__ bo,
    const float* __restrict__ Pout, float* __restrict__ out, int n)
{
  __shared__ unsigned short Xs[128 * LDXP];
  const int tid = threadIdx.x;
  const int lane = tid & 63;
  const int wave = tid >> 6;
  const int wm_ = wave >> 1;
  const int wn = wave & 1;
  const int l15 = lane & 15;
  const int quad = lane >> 4;
  const int row0 = blockIdx.x * 128;
  const int c8 = (tid & 15) * 8;
  const int rloc = tid >> 4;

  floatx4 acc[4][4];
#pragma unroll
  for (int i = 0; i < 4; ++i)
#pragma unroll
    for (int j = 0; j < 4; ++j) acc[i][j] = (floatx4){0.f, 0.f, 0.f, 0.f};

  const unsigned short* Xp[3] = {C, D, G2};
#pragma unroll
  for (int s = 0; s < 3; ++s) {
    if (s) __syncthreads();
    stage_bf16(Xp[s], Xs, row0, n, rloc, c8);
    __syncthreads();
    mfma_phase<4>(Wm + s * 128, 384, Xs, wm_, wn, l15, quad, acc);
  }
  __syncthreads();   // all K=384 reads done before A3 overwrite

  // A3 = relu(acc + bm) -> Xs (bf16)
#pragma unroll
  for (int i = 0; i < 4; ++i) {
    int r2 = wm_ * 64 + i * 16 + l15;
#pragma unroll
    for (int j = 0; j < 4; ++j) {
      int c2 = wn * 64 + j * 16 + quad * 4;
      float4 bb = *(const float4*)(bm + c2);
      float v0 = fmaxf(acc[i][j][0] + bb.x, 0.f);
      float v1 = fmaxf(acc[i][j][1] + bb.y, 0.f);
      float v2 = fmaxf(acc[i][j][2] + bb.z, 0.f);
      float v3 = fmaxf(acc[i][j][3] + bb.w, 0.f);
      uint2 o; o.x = pack2(v0, v1); o.y = pack2(v2, v3);
      *(uint2*)(Xs + r2 * LDXP + c2) = o;
    }
  }
  __syncthreads();

  floatx4 acc2[4][2];
#pragma unroll
  for (int i = 0; i < 4; ++i)
#pragma unroll
    for (int j = 0; j < 2; ++j) acc2[i][j] = (floatx4){0.f, 0.f, 0.f, 0.f};
  mfma_phase<2>(Wo1, 128, Xs, wm_, wn, l15, quad, acc2);

#pragma unroll
  for (int i = 0; i < 4; ++i) {
    int r = row0 + wm_ * 64 + i * 16 + l15;
    if (r >= n) continue;
#pragma unroll
    for (int j = 0; j < 2; ++j) {
      int c0 = wn * 32 + j * 16 + quad * 4;
      float4 bb = *(const float4*)(bo + c0);
      float4 pv = *(const float4*)(Pout + (size_t)r * 64 + c0);
      float4 o;
      o.x = acc2[i][j][0] + bb.x + pv.x;
      o.y = acc2[i][j][1] + bb.y + pv.y;
      o.z = acc2[i][j][2] + bb.z + pv.z;
      o.w = acc2[i][j][3] + bb.w + pv.w;
      *(float4*)(out + (size_t)r * 64 + c0) = o;
    }
  }
}

extern "C" void kernel_launch(void* const* d_in, const int* in_sizes, int n_in,
                              void* d_out, int out_size, void* d_ws, size_t ws_size,
                              hipStream_t stream)
{
  const float* x     = (const float*)d_in[0];
  const int*   row_a = (const int*)d_in[1];
  const int*   col_a = (const int*)d_in[2];
  const float* val_a = (const float*)d_in[3];
  const int*   row_b = (const int*)d_in[4];
  const int*   col_b = (const int*)d_in[5];
  const float* val_b = (const float*)d_in[6];
  const float* Wa0 = (const float*)d_in[7];  const float* ba0 = (const float*)d_in[8];
  const float* Wa1 = (const float*)d_in[9];  const float* ba1 = (const float*)d_in[10];
  const float* Wb0 = (const float*)d_in[11]; const float* bb0 = (const float*)d_in[12];
  const float* Wb1 = (const float*)d_in[13]; const float* bb1 = (const float*)d_in[14];
  const float* Wm  = (const float*)d_in[15]; const float* bm  = (const float*)d_in[16];
  const float* Wo  = (const float*)d_in[17]; const float* bo  = (const float*)d_in[18];
  float* out = (float*)d_out;

  const int n = in_sizes[0] / 128;   // 50000
  const int E = in_sizes[1];         // 800000

  char* ws = (char*)d_ws;
  size_t off = 0;
  auto alloc = [&](size_t bytes) {
    void* p = ws + off;
    off = (off + bytes + 255) & ~(size_t)255;
    return p;
  };
  int* rpa = (int*)alloc((size_t)(n + 1) * sizeof(int));
  int* rpb = (int*)alloc((size_t)(n + 1) * sizeof(int));
  unsigned short* Wcat = (unsigned short*)alloc(131072 * sizeof(unsigned short));
  const size_t slab = (size_t)n * 128 * sizeof(unsigned short);
  const size_t slab8 = (size_t)n * 128;           // fp8 slab (bytes)
  unsigned char*  A8 = (unsigned char*)alloc(slab8);   // fp8 relu(x Wa0 + ba0)
  unsigned short* C  = (unsigned short*)alloc(slab);   // g0 bf16
  unsigned char*  C8 = (unsigned char*)alloc(slab8);   // g0 fp8
  unsigned short* B  = (unsigned short*)alloc(slab);   // graph-a sp1 out / g2
  unsigned short* B2 = (unsigned short*)alloc(slab);   // graph-b sp1 out
  unsigned short* D  = (unsigned short*)alloc(slab);   // g1 bf16
  unsigned char*  D8 = (unsigned char*)alloc(slab8);   // g1 fp8
  unsigned char*  Q8 = (unsigned char*)alloc((size_t)n * 64);  // fp8 Q
  float* Pout = (float*)alloc((size_t)n * 64 * sizeof(float)); // x_a @ Wo0^T

  const unsigned short* Wa0b = Wcat;
  const unsigned short* Wa1b = Wcat + 16384;
  const unsigned short* Wb0b = Wcat + 32768;
  const unsigned short* Wb1b = Wcat + 49152;
  const unsigned short* Wmb  = Wcat + 65536;   // [128, 384]
  const unsigned short* Wo0b = Wcat + 114688;
  const unsigned short* Wo1b = Wcat + 122880;

  dim3 blk(256);
  dim3 g_setup((n + 1 + 255) / 256, 3);
  dim3 g_lin((n + 127) / 128);
  dim3 g_cg((n + 127) / 128, 2);
  dim3 g_sp2((n + 15) / 16, 2);

  setup_kernel<<<g_setup, blk, 0, stream>>>(row_a, row_b, E, n, rpa, rpb,
                                            Wa0, Wa1, Wb0, Wb1, Wm, Wo, Wcat);

  // A8 = fp8(relu(x Wa0^T + ba0)), C = relu(x Wb0^T + bb0) (bf16 + fp8)
  gemm_dual_f32_kernel<<<g_lin, blk, 0, stream>>>(x, Wa0b, Wb0b, ba0, bb0,
                                                  A8, C, C8, n);

  // spmm_a(A8->B) || spmm_b(C8->B2)   (fp8 gathers, 1 line/edge)
  spmm_dual128_kernel<<<g_sp2, blk, 0, stream>>>(
      rpa, col_a, val_a, A8, B,
      rpb, col_b, val_b, C8, B2, n);

  // chain: Q8 = fp8(relu(B Wa1^T + ba1) Wo0^T)  ||  g1: D (bf16+fp8)
  chain_g1_kernel<<<g_cg, blk, 0, stream>>>(
      B, Wa1b, ba1, Wo0b, Q8,
      B2, Wb1b, bb1, D, D8, n);

  // g2 = spmm_b(D8) -> B  ||  Pout = spmm_a(Q8)
  spmm_mixed_kernel<<<g_sp2, blk, 0, stream>>>(
      rpb, col_b, val_b, D8, B,
      rpa, col_a, val_a, Q8, Pout, n);

  // out = relu(g0 Wm0 + g1 Wm1 + g2 Wm2 + bm) Wo1^T + bo + Pout
  wm_final_kernel<<<g_lin, blk, 0, stream>>>(
      C, D, B, Wmb, bm, Wo1b, bo, Pout, out, n);
}

// Round 12
// 257.636 us; speedup vs baseline: 1.3651x; 1.0865x over previous
//
#include <hip/hip_runtime.h>

// ---------------------------------------------------------------------------
// DualGCN v14: v13 (fp8 gathers, best 279.9us) + SpMM issue-rate halving.
//   8 lanes/row x 16B uint4 gathers (full 128B fp8 row per wave-octet) and
//   packed float2 accumulation (v_pk_fma_f32 via __builtin_elementwise_fma):
//   per edge-lane 1 load + 8 cvt + 8 pk-fma for 16 values (was 13 ops for 8).
//   Memory pattern / depth-2 pipeline / numerics identical to v13.
// 6 launches. N=50000, E=800000, H=128, OUT=64.
// ---------------------------------------------------------------------------

typedef short short8 __attribute__((ext_vector_type(8)));
typedef float floatx4 __attribute__((ext_vector_type(4)));
typedef float floatx2 __attribute__((ext_vector_type(2)));

#define LDXP 136   // padded LDS row stride (bf16 units)

__device__ inline unsigned short f2bf(float f) {
  unsigned u = __builtin_bit_cast(unsigned, f);
  u += 0x7fffu + ((u >> 16) & 1u);      // round-to-nearest-even
  return (unsigned short)(u >> 16);
}
__device__ inline unsigned pack2(float a, float b) {
  return (unsigned)f2bf(a) | ((unsigned)f2bf(b) << 16);
}
__device__ inline float bf_lo(unsigned w) {
  return __builtin_bit_cast(float, w << 16);
}
__device__ inline float bf_hi(unsigned w) {
  return __builtin_bit_cast(float, w & 0xffff0000u);
}
// 4 floats -> 4 fp8 bytes (RNE, HW)
__device__ inline unsigned pack_fp8x4(float v0, float v1, float v2, float v3) {
  int p = 0;
  p = __builtin_amdgcn_cvt_pk_fp8_f32(v0, v1, p, false);   // bytes 0,1
  p = __builtin_amdgcn_cvt_pk_fp8_f32(v2, v3, p, true);    // bytes 2,3
  return (unsigned)p;
}

// y=0: rowptr for graph a; y=1: rowptr for graph b; y=2: convert weights.
// Wo de-interleaved into Wo0 = Wo[:, :128] and Wo1 = Wo[:, 128:].
__global__ __launch_bounds__(256) void setup_kernel(
    const int* __restrict__ rowA, const int* __restrict__ rowB,
    int E, int n, int* __restrict__ rpa, int* __restrict__ rpb,
    const float* __restrict__ Wa0, const float* __restrict__ Wa1,
    const float* __restrict__ Wb0, const float* __restrict__ Wb1,
    const float* __restrict__ Wm,  const float* __restrict__ Wo,
    unsigned short* __restrict__ Wout)
{
  if (blockIdx.y == 2) {
    for (int i = blockIdx.x * 256 + threadIdx.x; i < 131072; i += gridDim.x * 256) {
      float v;
      if      (i < 16384)  v = Wa0[i];
      else if (i < 32768)  v = Wa1[i - 16384];
      else if (i < 49152)  v = Wb0[i - 32768];
      else if (i < 65536)  v = Wb1[i - 49152];
      else if (i < 114688) v = Wm[i - 65536];
      else {
        int o = i - 114688;           // [0, 16384)
        int half = o >> 13;           // 0 -> Wo0, 1 -> Wo1
        int idx = o & 8191;
        int r = idx >> 7, c = idx & 127;
        v = Wo[r * 256 + half * 128 + c];
      }
      Wout[i] = f2bf(v);
    }
    return;
  }
  int i = blockIdx.x * blockDim.x + threadIdx.x;
  if (i > n) return;
  const int* row = blockIdx.y ? rowB : rowA;
  int* rp = blockIdx.y ? rpb : rpa;
  int lo = 0, hi = E;
  while (lo < hi) {
    int mid = (lo + hi) >> 1;
    if (row[mid] < i) lo = mid + 1; else hi = mid;
  }
  rp[i] = lo;
}

// ---------------------------------------------------------------------------
// SpMM row body, fp8 gathers, 16B/lane, packed-f32 accumulation.
// Y[g,:] = sum_e val[e] * X8[col[e],:]   (X8 fp8-e4m3, WIDTH features)
// WIDTH/16 lanes per row; each lane owns 16 features (8 floatx2 accums).
// Depth-2 pipeline: col/val prefetched 2 batches ahead.
// ---------------------------------------------------------------------------
template <int WIDTH, bool OUTF32>
__device__ __forceinline__ void spmm_rows_fp8(
    const int* __restrict__ rowptr, const int* __restrict__ col,
    const float* __restrict__ val, const unsigned char* __restrict__ X8,
    void* __restrict__ Yv, int n, int bx)
{
  constexpr int LPR = WIDTH / 16;       // lanes per row
  constexpr int GPB = 256 / LPR;        // row-groups per block
  int g = bx * GPB + ((int)threadIdx.x / LPR);
  int lane = threadIdx.x & (LPR - 1);
  if (g >= n) return;
  int e0 = rowptr[g], e1 = rowptr[g + 1];

  floatx2 ac[8];
#pragma unroll
  for (int k = 0; k < 8; ++k) ac[k] = (floatx2){0.f, 0.f};
  const size_t loff = (size_t)lane * 16;

  auto gat = [&](int c) -> uint4 {
    return *(const uint4*)(X8 + (size_t)c * WIDTH + loff);
  };
  auto fma1 = [&](float v, uint4 w) {
    const floatx2 vv = {v, v};
    floatx2 p;
    p = __builtin_amdgcn_cvt_pk_f32_fp8((int)w.x, false);
    ac[0] = __builtin_elementwise_fma(vv, p, ac[0]);
    p = __builtin_amdgcn_cvt_pk_f32_fp8((int)w.x, true);
    ac[1] = __builtin_elementwise_fma(vv, p, ac[1]);
    p = __builtin_amdgcn_cvt_pk_f32_fp8((int)w.y, false);
    ac[2] = __builtin_elementwise_fma(vv, p, ac[2]);
    p = __builtin_amdgcn_cvt_pk_f32_fp8((int)w.y, true);
    ac[3] = __builtin_elementwise_fma(vv, p, ac[3]);
    p = __builtin_amdgcn_cvt_pk_f32_fp8((int)w.z, false);
    ac[4] = __builtin_elementwise_fma(vv, p, ac[4]);
    p = __builtin_amdgcn_cvt_pk_f32_fp8((int)w.z, true);
    ac[5] = __builtin_elementwise_fma(vv, p, ac[5]);
    p = __builtin_amdgcn_cvt_pk_f32_fp8((int)w.w, false);
    ac[6] = __builtin_elementwise_fma(vv, p, ac[6]);
    p = __builtin_amdgcn_cvt_pk_f32_fp8((int)w.w, true);
    ac[7] = __builtin_elementwise_fma(vv, p, ac[7]);
  };
  auto accum = [&](int c, float v) { fma1(v, gat(c)); };

  int e = e0;
  int epro = (e0 + 3) & ~3;             // align to 4 for vector col/val loads
  if (epro > e1) epro = e1;
  for (; e < epro; ++e) accum(col[e], val[e]);

  int nb = (e1 - e) >> 2;               // full 4-edge batches
  if (nb > 0) {
    int4   cA = *(const int4*)(col + e);
    float4 vA = *(const float4*)(val + e);
    int4   cB = cA; float4 vB = vA;
    if (nb > 1) { cB = *(const int4*)(col + e + 4); vB = *(const float4*)(val + e + 4); }
    uint4 w0 = gat(cA.x), w1 = gat(cA.y), w2 = gat(cA.z), w3 = gat(cA.w);
    for (int t = 0; t < nb - 1; ++t) {
      int4 cC = cB; float4 vC = vB;
      if (t + 2 < nb) {
        cC = *(const int4*)(col + e + 4 * (t + 2));
        vC = *(const float4*)(val + e + 4 * (t + 2));
      }
      uint4 u0 = gat(cB.x), u1 = gat(cB.y), u2 = gat(cB.z), u3 = gat(cB.w);
      fma1(vA.x, w0); fma1(vA.y, w1); fma1(vA.z, w2); fma1(vA.w, w3);
      vA = vB; vB = vC; cB = cC;
      w0 = u0; w1 = u1; w2 = u2; w3 = u3;
    }
    fma1(vA.x, w0); fma1(vA.y, w1); fma1(vA.z, w2); fma1(vA.w, w3);
    e += nb * 4;
  }
  for (; e < e1; ++e) accum(col[e], val[e]);

  if (OUTF32) {
    float* Y = (float*)Yv;
#pragma unroll
    for (int q = 0; q < 4; ++q) {
      float4 o;
      o.x = ac[2 * q].x;     o.y = ac[2 * q].y;
      o.z = ac[2 * q + 1].x; o.w = ac[2 * q + 1].y;
      *(float4*)(Y + (size_t)g * WIDTH + lane * 16 + q * 4) = o;
    }
  } else {
    unsigned short* Y = (unsigned short*)Yv;
    uint4 o0, o1;
    o0.x = pack2(ac[0].x, ac[0].y); o0.y = pack2(ac[1].x, ac[1].y);
    o0.z = pack2(ac[2].x, ac[2].y); o0.w = pack2(ac[3].x, ac[3].y);
    o1.x = pack2(ac[4].x, ac[4].y); o1.y = pack2(ac[5].x, ac[5].y);
    o1.z = pack2(ac[6].x, ac[6].y); o1.w = pack2(ac[7].x, ac[7].y);
    *(uint4*)(Y + (size_t)g * WIDTH + lane * 16) = o0;
    *(uint4*)(Y + (size_t)g * WIDTH + lane * 16 + 8) = o1;
  }
}

// y=0: graph a, A8->B; y=1: graph b, C8->B2 (both 128-wide fp8 in, bf16 out)
__global__ __launch_bounds__(256) void spmm_dual128_kernel(
    const int* __restrict__ rpa, const int* __restrict__ cola,
    const float* __restrict__ vala, const unsigned char* __restrict__ A8,
    unsigned short* __restrict__ B,
    const int* __restrict__ rpb, const int* __restrict__ colb,
    const float* __restrict__ valb, const unsigned char* __restrict__ C8,
    unsigned short* __restrict__ B2, int n)
{
  if (blockIdx.y == 0)
    spmm_rows_fp8<128, false>(rpa, cola, vala, A8, B, n, blockIdx.x);
  else
    spmm_rows_fp8<128, false>(rpb, colb, valb, C8, B2, n, blockIdx.x);
}

// y=0: graph b 128-wide D8->Yb (bf16); y=1: graph a 64-wide Q8->Pout (f32)
__global__ __launch_bounds__(256) void spmm_mixed_kernel(
    const int* __restrict__ rpb, const int* __restrict__ colb,
    const float* __restrict__ valb, const unsigned char* __restrict__ D8,
    unsigned short* __restrict__ Yb,
    const int* __restrict__ rpa, const int* __restrict__ cola,
    const float* __restrict__ vala, const unsigned char* __restrict__ Q8,
    float* __restrict__ Pout, int n)
{
  if (blockIdx.y == 0)
    spmm_rows_fp8<128, false>(rpb, colb, valb, D8, Yb, n, blockIdx.x);
  else
    spmm_rows_fp8<64, true>(rpa, cola, vala, Q8, Pout, n, blockIdx.x);
}

// ---------------------------------------------------------------------------
// GEMM building blocks (v9 verbatim). Block: 256 thr = 4 waves 2x2;
// tile 128 rows x HOUT. X operand in LDS; W fragments from global.
// ---------------------------------------------------------------------------
__device__ inline void stage_bf16(const unsigned short* __restrict__ Xp,
                                  unsigned short* Xs, int row0, int n,
                                  int rloc, int c8)
{
#pragma unroll
  for (int p = 0; p < 8; ++p) {
    int r = p * 16 + rloc;
    int gr = row0 + r;
    uint4 v = make_uint4(0u, 0u, 0u, 0u);
    if (gr < n) v = *(const uint4*)(Xp + (size_t)gr * 128 + c8);
    *(uint4*)(Xs + r * LDXP + c8) = v;
  }
}

template <int NT>
__device__ inline void mfma_phase(const unsigned short* __restrict__ W, int wld,
                                  const unsigned short* Xs,
                                  int wm, int wn, int l15, int quad,
                                  floatx4 (&acc)[4][NT])
{
#pragma unroll
  for (int k0 = 0; k0 < 128; k0 += 32) {
    const int ko = k0 + quad * 8;
    short8 aW[NT], bX[4];
#pragma unroll
    for (int j = 0; j < NT; ++j)
      aW[j] = *(const short8*)(W + (size_t)(wn * (16 * NT) + j * 16 + l15) * wld + ko);
#pragma unroll
    for (int i = 0; i < 4; ++i)
      bX[i] = *(const short8*)(Xs + (wm * 64 + i * 16 + l15) * LDXP + ko);
#pragma unroll
    for (int i = 0; i < 4; ++i)
#pragma unroll
      for (int j = 0; j < NT; ++j)
        acc[i][j] = __builtin_amdgcn_mfma_f32_16x16x32_bf16(aW[j], bX[i], acc[i][j], 0, 0, 0);
  }
}

// A8 = fp8(relu(x@W1.T+b1)) [spmm-only], C = relu(x@W2.T+b2) bf16 + C8 fp8.
__global__ __launch_bounds__(256, 2) void gemm_dual_f32_kernel(
    const float* __restrict__ X, const unsigned short* __restrict__ W1,
    const unsigned short* __restrict__ W2, const float* __restrict__ b1,
    const float* __restrict__ b2, unsigned char* __restrict__ A8,
    unsigned short* __restrict__ C, unsigned char* __restrict__ C8, int n)
{
  constexpr int NT = 4;  // HOUT = 128
  __shared__ unsigned short Xs[128 * LDXP];
  const int tid = threadIdx.x;
  const int lane = tid & 63;
  const int wave = tid >> 6;
  const int wm = wave >> 1;
  const int wn = wave & 1;
  const int l15 = lane & 15;
  const int quad = lane >> 4;
  const int row0 = blockIdx.x * 128;
  const int c8 = (tid & 15) * 8;
  const int rloc = tid >> 4;

#pragma unroll
  for (int p = 0; p < 8; ++p) {
    int r = p * 16 + rloc;
    int gr = row0 + r;
    uint4 o = make_uint4(0u, 0u, 0u, 0u);
    if (gr < n) {
      float4 f0 = *(const float4*)(X + (size_t)gr * 128 + c8);
      float4 f1 = *(const float4*)(X + (size_t)gr * 128 + c8 + 4);
      o.x = pack2(f0.x, f0.y); o.y = pack2(f0.z, f0.w);
      o.z = pack2(f1.x, f1.y); o.w = pack2(f1.z, f1.w);
    }
    *(uint4*)(Xs + r * LDXP + c8) = o;
  }
  __syncthreads();

  for (int s = 0; s < 2; ++s) {
    const unsigned short* W = s ? W2 : W1;
    const float* b = s ? b2 : b1;
    floatx4 acc[4][NT];
#pragma unroll
    for (int i = 0; i < 4; ++i)
#pragma unroll
      for (int j = 0; j < NT; ++j) acc[i][j] = (floatx4){0.f, 0.f, 0.f, 0.f};
    mfma_phase<NT>(W, 128, Xs, wm, wn, l15, quad, acc);
#pragma unroll
    for (int i = 0; i < 4; ++i) {
      int r = row0 + wm * 64 + i * 16 + l15;
      if (r >= n) continue;
#pragma unroll
      for (int j = 0; j < NT; ++j) {
        int c0 = wn * 64 + j * 16 + quad * 4;
        float4 bb = *(const float4*)(b + c0);
        float v0 = fmaxf(acc[i][j][0] + bb.x, 0.f);
        float v1 = fmaxf(acc[i][j][1] + bb.y, 0.f);
        float v2 = fmaxf(acc[i][j][2] + bb.z, 0.f);
        float v3 = fmaxf(acc[i][j][3] + bb.w, 0.f);
        unsigned p8 = pack_fp8x4(v0, v1, v2, v3);
        if (s == 0) {
          *(unsigned*)(A8 + (size_t)r * 128 + c0) = p8;      // A: fp8 only
        } else {
          uint2 o; o.x = pack2(v0, v1); o.y = pack2(v2, v3);
          *(uint2*)(C + (size_t)r * 128 + c0) = o;           // C: bf16 (GEMM)
          *(unsigned*)(C8 + (size_t)r * 128 + c0) = p8;      // C: fp8 (spmm)
        }
      }
    }
  }
}

// y=0: Q8 = fp8((relu(B·Wa1^T+ba1))·Wo0^T) (chained through LDS, spmm-only)
// y=1: D = relu(B2·Wb1^T+bb1) bf16 + D8 fp8
__global__ __launch_bounds__(256, 2) void chain_g1_kernel(
    const unsigned short* __restrict__ B, const unsigned short* __restrict__ Wa1,
    const float* __restrict__ ba1, const unsigned short* __restrict__ Wo0,
    unsigned char* __restrict__ Q8,
    const unsigned short* __restrict__ B2, const unsigned short* __restrict__ Wb1,
    const float* __restrict__ bb1, unsigned short* __restrict__ D,
    unsigned char* __restrict__ D8, int n)
{
  __shared__ unsigned short Xs[128 * LDXP];
  const int tid = threadIdx.x;
  const int lane = tid & 63;
  const int wave = tid >> 6;
  const int wm = wave >> 1;
  const int wn = wave & 1;
  const int l15 = lane & 15;
  const int quad = lane >> 4;
  const int row0 = blockIdx.x * 128;
  const int c8 = (tid & 15) * 8;
  const int rloc = tid >> 4;

  if (blockIdx.y == 0) {
    stage_bf16(B, Xs, row0, n, rloc, c8);
    __syncthreads();

    floatx4 acc1[4][4];
#pragma unroll
    for (int i = 0; i < 4; ++i)
#pragma unroll
      for (int j = 0; j < 4; ++j) acc1[i][j] = (floatx4){0.f, 0.f, 0.f, 0.f};
    mfma_phase<4>(Wa1, 128, Xs, wm, wn, l15, quad, acc1);
    __syncthreads();   // all stage-1 reads of Xs done before overwrite

    // A2 = relu(acc1 + ba1) -> Xs (bf16)
#pragma unroll
    for (int i = 0; i < 4; ++i) {
      int r2 = wm * 64 + i * 16 + l15;
#pragma unroll
      for (int j = 0; j < 4; ++j) {
        int c2 = wn * 64 + j * 16 + quad * 4;
        float4 bb = *(const float4*)(ba1 + c2);
        float v0 = fmaxf(acc1[i][j][0] + bb.x, 0.f);
        float v1 = fmaxf(acc1[i][j][1] + bb.y, 0.f);
        float v2 = fmaxf(acc1[i][j][2] + bb.z, 0.f);
        float v3 = fmaxf(acc1[i][j][3] + bb.w, 0.f);
        uint2 o; o.x = pack2(v0, v1); o.y = pack2(v2, v3);
        *(uint2*)(Xs + r2 * LDXP + c2) = o;
      }
    }
    __syncthreads();

    floatx4 acc2[4][2];
#pragma unroll
    for (int i = 0; i < 4; ++i)
#pragma unroll
      for (int j = 0; j < 2; ++j) acc2[i][j] = (floatx4){0.f, 0.f, 0.f, 0.f};
    mfma_phase<2>(Wo0, 128, Xs, wm, wn, l15, quad, acc2);

#pragma unroll
    for (int i = 0; i < 4; ++i) {
      int r = row0 + wm * 64 + i * 16 + l15;
      if (r >= n) continue;
#pragma unroll
      for (int j = 0; j < 2; ++j) {
        int c0 = wn * 32 + j * 16 + quad * 4;
        unsigned p8 = pack_fp8x4(acc2[i][j][0], acc2[i][j][1],
                                 acc2[i][j][2], acc2[i][j][3]);
        *(unsigned*)(Q8 + (size_t)r * 64 + c0) = p8;
      }
    }
  } else {
    stage_bf16(B2, Xs, row0, n, rloc, c8);
    __syncthreads();

    floatx4 acc[4][4];
#pragma unroll
    for (int i = 0; i < 4; ++i)
#pragma unroll
      for (int j = 0; j < 4; ++j) acc[i][j] = (floatx4){0.f, 0.f, 0.f, 0.f};
    mfma_phase<4>(Wb1, 128, Xs, wm, wn, l15, quad, acc);

#pragma unroll
    for (int i = 0; i < 4; ++i) {
      int r = row0 + wm * 64 + i * 16 + l15;
      if (r >= n) continue;
#pragma unroll
      for (int j = 0; j < 4; ++j) {
        int c0 = wn * 64 + j * 16 + quad * 4;
        float4 bb = *(const float4*)(bb1 + c0);
        float v0 = fmaxf(acc[i][j][0] + bb.x, 0.f);
        float v1 = fmaxf(acc[i][j][1] + bb.y, 0.f);
        float v2 = fmaxf(acc[i][j][2] + bb.z, 0.f);
        float v3 = fmaxf(acc[i][j][3] + bb.w, 0.f);
        uint2 o; o.x = pack2(v0, v1); o.y = pack2(v2, v3);
        *(uint2*)(D + (size_t)r * 128 + c0) = o;             // bf16 (GEMM)
        *(unsigned*)(D8 + (size_t)r * 128 + c0) = pack_fp8x4(v0, v1, v2, v3);
      }
    }
  }
}

// out = relu(C·Wm0 + D·Wm1 + G2·Wm2 + bm)·Wo1^T + bo + Pout  (A3 in LDS only)
__global__ __launch_bounds__(256, 2) void wm_final_kernel(
    const unsigned short* __restrict__ C, const unsigned short* __restrict__ D,
    const unsigned short* __restrict__ G2,
    const unsigned short* __restrict__ Wm, const float* __restrict__ bm,
    const unsigned short* __restrict__ Wo1, const float* __restrict__ bo,
    const float* __restrict__ Pout, float* __restrict__ out, int n)
{
  __shared__ unsigned short Xs[128 * LDXP];
  const int tid = threadIdx.x;
  const int lane = tid & 63;
  const int wave = tid >> 6;
  const int wm_ = wave >> 1;
  const int wn = wave & 1;
  const int l15 = lane & 15;
  const int quad = lane >> 4;
  const int row0 = blockIdx.x * 128;
  const int c8 = (tid & 15) * 8;
  const int rloc = tid >> 4;

  floatx4 acc[4][4];
#pragma unroll
  for (int i = 0; i < 4; ++i)
#pragma unroll
    for (int j = 0; j < 4; ++j) acc[i][j] = (floatx4){0.f, 0.f, 0.f, 0.f};

  const unsigned short* Xp[3] = {C, D, G2};
#pragma unroll
  for (int s = 0; s < 3; ++s) {
    if (s) __syncthreads();
    stage_bf16(Xp[s], Xs, row0, n, rloc, c8);
    __syncthreads();
    mfma_phase<4>(Wm + s * 128, 384, Xs, wm_, wn, l15, quad, acc);
  }
  __syncthreads();   // all K=384 reads done before A3 overwrite

  // A3 = relu(acc + bm) -> Xs (bf16)
#pragma unroll
  for (int i = 0; i < 4; ++i) {
    int r2 = wm_ * 64 + i * 16 + l15;
#pragma unroll
    for (int j = 0; j < 4; ++j) {
      int c2 = wn * 64 + j * 16 + quad * 4;
      float4 bb = *(const float4*)(bm + c2);
      float v0 = fmaxf(acc[i][j][0] + bb.x, 0.f);
      float v1 = fmaxf(acc[i][j][1] + bb.y, 0.f);
      float v2 = fmaxf(acc[i][j][2] + bb.z, 0.f);
      float v3 = fmaxf(acc[i][j][3] + bb.w, 0.f);
      uint2 o; o.x = pack2(v0, v1); o.y = pack2(v2, v3);
      *(uint2*)(Xs + r2 * LDXP + c2) = o;
    }
  }
  __syncthreads();

  floatx4 acc2[4][2];
#pragma unroll
  for (int i = 0; i < 4; ++i)
#pragma unroll
    for (int j = 0; j < 2; ++j) acc2[i][j] = (floatx4){0.f, 0.f, 0.f, 0.f};
  mfma_phase<2>(Wo1, 128, Xs, wm_, wn, l15, quad, acc2);

#pragma unroll
  for (int i = 0; i < 4; ++i) {
    int r = row0 + wm_ * 64 + i * 16 + l15;
    if (r >= n) continue;
#pragma unroll
    for (int j = 0; j < 2; ++j) {
      int c0 = wn * 32 + j * 16 + quad * 4;
      float4 bb = *(const float4*)(bo + c0);
      float4 pv = *(const float4*)(Pout + (size_t)r * 64 + c0);
      float4 o;
      o.x = acc2[i][j][0] + bb.x + pv.x;
      o.y = acc2[i][j][1] + bb.y + pv.y;
      o.z = acc2[i][j][2] + bb.z + pv.z;
      o.w = acc2[i][j][3] + bb.w + pv.w;
      *(float4*)(out + (size_t)r * 64 + c0) = o;
    }
  }
}

extern "C" void kernel_launch(void* const* d_in, const int* in_sizes, int n_in,
                              void* d_out, int out_size, void* d_ws, size_t ws_size,
                              hipStream_t stream)
{
  const float* x     = (const float*)d_in[0];
  const int*   row_a = (const int*)d_in[1];
  const int*   col_a = (const int*)d_in[2];
  const float* val_a = (const float*)d_in[3];
  const int*   row_b = (const int*)d_in[4];
  const int*   col_b = (const int*)d_in[5];
  const float* val_b = (const float*)d_in[6];
  const float* Wa0 = (const float*)d_in[7];  const float* ba0 = (const float*)d_in[8];
  const float* Wa1 = (const float*)d_in[9];  const float* ba1 = (const float*)d_in[10];
  const float* Wb0 = (const float*)d_in[11]; const float* bb0 = (const float*)d_in[12];
  const float* Wb1 = (const float*)d_in[13]; const float* bb1 = (const float*)d_in[14];
  const float* Wm  = (const float*)d_in[15]; const float* bm  = (const float*)d_in[16];
  const float* Wo  = (const float*)d_in[17]; const float* bo  = (const float*)d_in[18];
  float* out = (float*)d_out;

  const int n = in_sizes[0] / 128;   // 50000
  const int E = in_sizes[1];         // 800000

  char* ws = (char*)d_ws;
  size_t off = 0;
  auto alloc = [&](size_t bytes) {
    void* p = ws + off;
    off = (off + bytes + 255) & ~(size_t)255;
    return p;
  };
  int* rpa = (int*)alloc((size_t)(n + 1) * sizeof(int));
  int* rpb = (int*)alloc((size_t)(n + 1) * sizeof(int));
  unsigned short* Wcat = (unsigned short*)alloc(131072 * sizeof(unsigned short));
  const size_t slab = (size_t)n * 128 * sizeof(unsigned short);
  const size_t slab8 = (size_t)n * 128;           // fp8 slab (bytes)
  unsigned char*  A8 = (unsigned char*)alloc(slab8);   // fp8 relu(x Wa0 + ba0)
  unsigned short* C  = (unsigned short*)alloc(slab);   // g0 bf16
  unsigned char*  C8 = (unsigned char*)alloc(slab8);   // g0 fp8
  unsigned short* B  = (unsigned short*)alloc(slab);   // graph-a sp1 out / g2
  unsigned short* B2 = (unsigned short*)alloc(slab);   // graph-b sp1 out
  unsigned short* D  = (unsigned short*)alloc(slab);   // g1 bf16
  unsigned char*  D8 = (unsigned char*)alloc(slab8);   // g1 fp8
  unsigned char*  Q8 = (unsigned char*)alloc((size_t)n * 64);  // fp8 Q
  float* Pout = (float*)alloc((size_t)n * 64 * sizeof(float)); // x_a @ Wo0^T

  const unsigned short* Wa0b = Wcat;
  const unsigned short* Wa1b = Wcat + 16384;
  const unsigned short* Wb0b = Wcat + 32768;
  const unsigned short* Wb1b = Wcat + 49152;
  const unsigned short* Wmb  = Wcat + 65536;   // [128, 384]
  const unsigned short* Wo0b = Wcat + 114688;
  const unsigned short* Wo1b = Wcat + 122880;

  dim3 blk(256);
  dim3 g_setup((n + 1 + 255) / 256, 3);
  dim3 g_lin((n + 127) / 128);
  dim3 g_cg((n + 127) / 128, 2);
  dim3 g_sp2((n + 31) / 32, 2);      // 32 rows/block (8 lanes/row, 128-wide)

  setup_kernel<<<g_setup, blk, 0, stream>>>(row_a, row_b, E, n, rpa, rpb,
                                            Wa0, Wa1, Wb0, Wb1, Wm, Wo, Wcat);

  // A8 = fp8(relu(x Wa0^T + ba0)), C = relu(x Wb0^T + bb0) (bf16 + fp8)
  gemm_dual_f32_kernel<<<g_lin, blk, 0, stream>>>(x, Wa0b, Wb0b, ba0, bb0,
                                                  A8, C, C8, n);

  // spmm_a(A8->B) || spmm_b(C8->B2)   (fp8 gathers, 16B/lane)
  spmm_dual128_kernel<<<g_sp2, blk, 0, stream>>>(
      rpa, col_a, val_a, A8, B,
      rpb, col_b, val_b, C8, B2, n);

  // chain: Q8 = fp8(relu(B Wa1^T + ba1) Wo0^T)  ||  g1: D (bf16+fp8)
  chain_g1_kernel<<<g_cg, blk, 0, stream>>>(
      B, Wa1b, ba1, Wo0b, Q8,
      B2, Wb1b, bb1, D, D8, n);

  // g2 = spmm_b(D8) -> B  ||  Pout = spmm_a(Q8)
  spmm_mixed_kernel<<<g_sp2, blk, 0, stream>>>(
      rpb, col_b, val_b, D8, B,
      rpa, col_a, val_a, Q8, Pout, n);

  // out = relu(g0 Wm0 + g1 Wm1 + g2 Wm2 + bm) Wo1^T + bo + Pout
  wm_final_kernel<<<g_lin, blk, 0, stream>>>(
      C, D, B, Wmb, bm, Wo1b, bo, Pout, out, n);
}